// Round 11
// baseline (272.373 us; speedup 1.0000x reference)
//
#include <hip/hip_runtime.h>
#include <cstddef>
#include <cstdint>

#define N_NODES 10000
#define N_EDGES 160000

// ---- constants ----
#define RS8    0.35355339059327373f   // 1/sqrt(8)
#define RS32   0.17677669529663687f   // 1/sqrt(32)
#define RS96   0.10206207261596575f   // 1/sqrt(96)
#define RS128  0.08838834764831845f   // 1/sqrt(128)
#define RS3    0.5773502691896258f    // 1/sqrt(3)
#define SQ3_   1.7320508075688772f
#define SQ5_   2.23606797749979f
#define A_     0.18257418583505536f   // 1/sqrt(30)
#define B_     0.31622776601683794f   // 1/sqrt(10)
#define SILU_C_ 1.6765208f
#define CS_    0.3826834323650898f    // sin(pi/8)
#define CX_    0.9238795325112867f    // cos(pi/8)
#define QDEG   0.25f                  // 1/sqrt(16)

typedef __attribute__((ext_vector_type(8))) short bf16x8;
typedef __attribute__((ext_vector_type(4))) float f32x4;

__device__ inline float bf2f(unsigned v) {
  union { unsigned u; float f; } c; c.u = v << 16; return c.f;
}
__device__ inline float bfhi(unsigned v) {   // float from HIGH 16 bits
  union { unsigned u; float f; } c; c.u = v & 0xffff0000u; return c.f;
}
__device__ inline unsigned short f2bf(float f) {
  union { float f; unsigned u; } c; c.f = f;
  unsigned r = c.u + 0x7fff + ((c.u >> 16) & 1);
  return (unsigned short)(r >> 16);
}
__device__ inline unsigned pack2bf(float a, float b) {
  return (unsigned)f2bf(a) | ((unsigned)f2bf(b) << 16);
}
__device__ inline float silu_c(float x) {
  return SILU_C_ * x / (1.f + __expf(-x));
}

// k_prep: fused (counts pre-zeroed by hipMemsetAsync):
//  blocks [0,625)     : edge-dst histogram (atomics)
//  blocks [625,713)   : fc1p (K=0.125 FOLDED IN — exact pow2, bit-identical
//                       downstream) + fc0p packs
//  blocks [713,2233)  : Wp[1120][320] + Wyp[160][192] (verified MFMA
//                       first-operand fragment order, scales folded)
__global__ __launch_bounds__(256) void k_prep(
    const int* __restrict__ edst, int* __restrict__ counts,
    const float* __restrict__ fc1, unsigned short* __restrict__ fc1p,
    const float* __restrict__ fc0, unsigned short* __restrict__ fc0p,
    const float* __restrict__ sc_w0, const float* __restrict__ sc_w1,
    const float* __restrict__ w0, const float* __restrict__ w1,
    const float* __restrict__ w2, const float* __restrict__ l1_w0,
    const float* __restrict__ l1_w1, unsigned short* __restrict__ Wp,
    unsigned short* __restrict__ Wyp) {
  int b = blockIdx.x, t = threadIdx.x;
  if (b < 625) {
    int e = b * 256 + t;
    if (e < N_EDGES) atomicAdd(&counts[edst[e]], 1);
    return;
  }
  if (b < 713) {
    int i = (b - 625) * 256 + t;
    if (i < 20480) {
      int j = i & 7, q = (i >> 3) & 3, n = (i >> 5) & 15, kq = (i >> 9) & 1, tt = i >> 10;
      int k = kq * 32 + q * 8 + j;
      fc1p[i] = f2bf(0.125f * fc1[k * 320 + tt * 16 + n]);
    } else if (i < 22528) {
      int ii = i - 20480;
      int j = ii & 7;
      int lane = (ii >> 3) & 63;
      int ch = lane & 15, quad = lane >> 4;
      int nt = ii >> 9;                  // [0,4)
      int k = quad * 8 + j;
      float v = (k < 8) ? RS8 * fc0[k * 64 + nt * 16 + ch] : 0.f;
      fc0p[ii] = f2bf(v);
    }
    return;
  }
  int i = (b - 713) * 256 + t;
  if (i < 358400) {
    int j = i & 7;
    int lane = (i >> 3) & 63;
    int ch = lane & 15, quad = lane >> 4;
    int r = i >> 9;                    // [0,700)
    int nt = r / 35, ks = r - nt * 35;
    int k = ks * 32 + quad * 8 + j;
    int oc = nt * 16 + ch;
    float v = 0.f;
    if (k < 96) {                                   // m0 -> oc [0,64)
      if (oc < 64) v = (CX_ * RS96) * w0[k * 64 + oc];
    } else if (k < 480) {                           // m1 -> oc [64,160)
      int tt = k - 96, u = tt / 3, ii = tt - u * 3;
      if (oc >= 64 && oc < 160) {
        int d = oc - 64, vv = d / 3, jj = d - vv * 3;
        if (jj == ii) v = (CX_ * RS128) * w1[u * 32 + vv];
      }
    } else if (k < 960) {                           // m2 -> oc [160,320)
      int tt = k - 480, u = tt / 5, kk = tt - u * 5;
      if (oc >= 160) {
        int d = oc - 160, vv = d / 5, jj = d - vv * 5;
        if (jj == kk) v = RS96 * w2[u * 32 + vv];
      }
    } else if (k < 1024) {                          // x0 sc -> oc [0,64)
      int u = k - 960;
      if (oc < 64) v = (CS_ * 0.125f) * sc_w0[u * 64 + oc];
    } else {                                        // x1 sc -> oc [64,160)
      int tt = k - 1024, u = tt / 3, ii = tt - u * 3;
      if (oc >= 64 && oc < 160) {
        int d = oc - 64, vv = d / 3, jj = d - vv * 3;
        if (jj == ii) v = (CS_ * RS32) * sc_w1[u * 32 + vv];
      }
    }
    Wp[i] = f2bf(v);
  } else if (i < 358400 + 30720) {
    // Wyp: y[n, 0:192] = attr * (x[n,0:160] @ Wy). KS=5, NT=12.
    int ii2 = i - 358400;
    int j = ii2 & 7;
    int lane = (ii2 >> 3) & 63;
    int ch = lane & 15, quad = lane >> 4;
    int r = ii2 >> 9;                  // [0,60)
    int nt = r / 5, ks = r - nt * 5;
    int k = ks * 32 + quad * 8 + j;    // [0,160)
    int oc = nt * 16 + ch;             // [0,192)
    float v = 0.f;
    if (k < 64) {
      if (oc < 64) v = 0.125f * l1_w0[k * 64 + oc];
    } else {
      int tt = k - 64, u = tt / 3, ci = tt - u * 3;   // u<32, ci<3
      if (oc >= 64) {
        int d = oc - 64, vv = d >> 2, jj = d & 3;
        if (jj == ci) v = RS32 * l1_w1[u * 32 + vv];  // jj==3 never matches
      }
    }
    Wyp[ii2] = f2bf(v);
  }
}

// exclusive scan of counts -> offs/cur; degree histogram + descending-degree
// exclusive scan -> dcur (single block).
__global__ __launch_bounds__(256) void k_scan(const int* __restrict__ counts,
                                              int* __restrict__ offs,
                                              int* __restrict__ cur,
                                              int* __restrict__ dcur) {
  __shared__ int ps[256];
  __shared__ int dbin[256];
  int t = threadIdx.x;
  dbin[t] = 0;
  int base = t * 40;
  int sum = 0;
  for (int i = 0; i < 40; ++i) {
    int idx = base + i;
    if (idx < N_NODES) sum += counts[idx];
  }
  ps[t] = sum;
  __syncthreads();
  for (int off = 1; off < 256; off <<= 1) {
    int v = (t >= off) ? ps[t - off] : 0;
    __syncthreads();
    ps[t] += v;
    __syncthreads();
  }
  int run = (t == 0) ? 0 : ps[t - 1];
  for (int i = 0; i < 40; ++i) {
    int idx = base + i;
    if (idx < N_NODES) {
      int c = counts[idx];
      offs[idx] = run; cur[idx] = run;
      run += c;
      atomicAdd(&dbin[c < 255 ? c : 255], 1);
    }
  }
  __syncthreads();
  int rb = 255 - t;
  int v = dbin[rb];
  __syncthreads();
  ps[t] = v;
  __syncthreads();
  for (int off = 1; off < 256; off <<= 1) {
    int u = (t >= off) ? ps[t - off] : 0;
    __syncthreads();
    ps[t] += u;
    __syncthreads();
  }
  dcur[rb] = ps[t] - v;
}

// Permute kernel: scatter-write ed2a (stride 12 f: SH+src) and ed2b
// (stride 8 f: ele); node scatter (degree-desc rank -> order/obeg/ocnt).
__global__ __launch_bounds__(256) void k_perm(
    const int* __restrict__ edst, int* __restrict__ cur,
    const int* __restrict__ counts, const int* __restrict__ offs,
    int* __restrict__ dcur, int* __restrict__ order,
    int* __restrict__ obeg, int* __restrict__ ocnt,
    const float* __restrict__ ele, const float* __restrict__ eattr,
    const int* __restrict__ esrc, float* __restrict__ ed2a,
    float* __restrict__ ed2b) {
  __shared__ __align__(16) float sh_ea[256 * 9];
  __shared__ __align__(16) float sh_el[256 * 8];
  int t = threadIdx.x;
  int eb = blockIdx.x * 256;
  int e = eb + t;
  for (int i = t; i < 2304; i += 256) sh_ea[i] = eattr[(size_t)eb * 9 + i];
  {
    const float4* src = (const float4*)(ele + (size_t)eb * 8);
    float4* dst = (float4*)sh_el;
    dst[t] = src[t]; dst[t + 256] = src[t + 256];
  }
  __syncthreads();
  int d = edst[e];
  int p = atomicAdd(&cur[d], 1);
  const float* ea = sh_ea + t * 9;
  const float* el = sh_el + t * 8;
  float4 r0 = {ea[0], ea[1], ea[2], ea[3]};
  float4 r1 = {ea[4], ea[5], ea[6], ea[7]};
  float4 r2 = {ea[8], __int_as_float(esrc[e]), 0.f, 0.f};
  float4* da = (float4*)(ed2a + (size_t)p * 12);
  da[0] = r0; da[1] = r1; da[2] = r2;
  float4 r3 = {el[0], el[1], el[2], el[3]};
  float4 r4 = {el[4], el[5], el[6], el[7]};
  float4* db = (float4*)(ed2b + (size_t)p * 8);
  db[0] = r3; db[1] = r4;
  if (e < N_NODES) {
    int c = counts[e];
    int b = c < 255 ? c : 255;
    int q = atomicAdd(&dcur[b], 1);
    order[q] = e; obeg[q] = offs[e]; ocnt[q] = c;
  }
}

// wtile: verified MFMA micro-GEMM (fc1p first-operand fragments).
__device__ inline f32x4 wtile(const unsigned short* __restrict__ fc1p,
                              bf16x8 a0, bf16x8 a1, int mrow, int quad, int t) {
  f32x4 acc = {0.f, 0.f, 0.f, 0.f};
  bf16x8 b0 = *(const bf16x8*)(fc1p + ((size_t)((t * 2 + 0) * 16 + mrow) * 4 + quad) * 8);
  bf16x8 b1 = *(const bf16x8*)(fc1p + ((size_t)((t * 2 + 1) * 16 + mrow) * 4 + quad) * 8);
  acc = __builtin_amdgcn_mfma_f32_16x16x32_bf16(b0, a0, acc, 0, 0, 0);
  acc = __builtin_amdgcn_mfma_f32_16x16x32_bf16(b1, a1, acc, 0, 0, 0);
  return acc;
}

struct WgemmShared {
  __align__(16) unsigned short elb[64 * 32];   // 4KB: ele bf16, K padded 8->32
  __align__(16) unsigned short h[64 * 72];     // 9KB, 72-stride pad
};

// h-GEMM: 64 edges/block, h-phase MFMA (verified r7), then dump h to
// global hbuf (128 B/edge, coalesced). The 102 MB wbuf pack is GONE —
// node_agg now recomputes w on the fly from h (fused w-GEMM).
__device__ void w_gemm_body(WgemmShared& sh, int blk,
    const float* __restrict__ ed2b, const unsigned short* __restrict__ fc0p,
    unsigned short* __restrict__ hout) {
  int t = threadIdx.x;
  int eb = blk * 64;
  {
    int e = t >> 2, q = t & 3;
    uint4 pk = {0u, 0u, 0u, 0u};
    if (q == 0) {
      const float4* ep = (const float4*)(ed2b + (size_t)(eb + e) * 8);
      float4 u = ep[0], v = ep[1];
      pk.x = pack2bf(u.x, u.y); pk.y = pack2bf(u.z, u.w);
      pk.z = pack2bf(v.x, v.y); pk.w = pack2bf(v.z, v.w);
    }
    *(uint4*)(sh.elb + e * 32 + q * 8) = pk;
  }
  __syncthreads();

  int wv = t >> 6, lane = t & 63;
  int ch16 = lane & 15, quad = lane >> 4;
  {
    bf16x8 af = *(const bf16x8*)(sh.elb + (wv * 16 + ch16) * 32 + quad * 8);
    bf16x8 b0 = *(const bf16x8*)(fc0p + 0 * 512 + lane * 8);
    bf16x8 b1 = *(const bf16x8*)(fc0p + 1 * 512 + lane * 8);
    bf16x8 b2 = *(const bf16x8*)(fc0p + 2 * 512 + lane * 8);
    bf16x8 b3 = *(const bf16x8*)(fc0p + 3 * 512 + lane * 8);
    f32x4 z = {0.f, 0.f, 0.f, 0.f};
    f32x4 h0 = __builtin_amdgcn_mfma_f32_16x16x32_bf16(b0, af, z, 0, 0, 0);
    f32x4 h1 = __builtin_amdgcn_mfma_f32_16x16x32_bf16(b1, af, z, 0, 0, 0);
    f32x4 h2 = __builtin_amdgcn_mfma_f32_16x16x32_bf16(b2, af, z, 0, 0, 0);
    f32x4 h3 = __builtin_amdgcn_mfma_f32_16x16x32_bf16(b3, af, z, 0, 0, 0);
    unsigned short* hb = sh.h + (wv * 16 + ch16) * 72 + quad * 4;
    uint2 s;
    s.x = pack2bf(silu_c(h0[0]), silu_c(h0[1]));
    s.y = pack2bf(silu_c(h0[2]), silu_c(h0[3]));
    *(uint2*)(hb + 0) = s;
    s.x = pack2bf(silu_c(h1[0]), silu_c(h1[1]));
    s.y = pack2bf(silu_c(h1[2]), silu_c(h1[3]));
    *(uint2*)(hb + 16) = s;
    s.x = pack2bf(silu_c(h2[0]), silu_c(h2[1]));
    s.y = pack2bf(silu_c(h2[2]), silu_c(h2[3]));
    *(uint2*)(hb + 32) = s;
    s.x = pack2bf(silu_c(h3[0]), silu_c(h3[1]));
    s.y = pack2bf(silu_c(h3[2]), silu_c(h3[3]));
    *(uint2*)(hb + 48) = s;
  }
  __syncthreads();

  // dump h (64 edges x 64 ch bf16) -> hbuf, coalesced 128 B rows
  for (int i = t; i < 2048; i += 256) {
    int row = i >> 5, col = i & 31;
    *(unsigned*)(hout + (size_t)(eb + row) * 64 + col * 2) =
        *(const unsigned*)(sh.h + row * 72 + col * 2);
  }
}

// k_npre body (MFMA): y[n, 0:192] = attr[n] * (bf16(xin[n,0:160]) @ Wyp).
#define YSTR 168
__device__ void npre_body(unsigned short* Ash, int blk,
    const float* __restrict__ xin, const float* __restrict__ attr,
    const unsigned short* __restrict__ Wyp, float* __restrict__ y) {
  int t = threadIdx.x;
  int nbase = blk * 16;
  for (int idx = t; idx < 16 * 80; idx += 256) {
    int row = idx / 80, c = idx - row * 80;
    const float* xp = xin + (size_t)(nbase + row) * 160 + 2 * c;
    *(unsigned*)(Ash + row * YSTR + 2 * c) = pack2bf(xp[0], xp[1]);
  }
  __syncthreads();
  int wid = t >> 6, lane = t & 63;
  int ch = lane & 15, quad = lane >> 4;
  const unsigned short* arow = Ash + ch * YSTR + quad * 8;
  f32x4 acc0 = {0.f,0.f,0.f,0.f}, acc1 = {0.f,0.f,0.f,0.f}, acc2 = {0.f,0.f,0.f,0.f};
  const unsigned short* wq0 = Wyp + ((size_t)(wid * 3 + 0) * 5 * 64 + lane) * 8;
  const unsigned short* wq1 = Wyp + ((size_t)(wid * 3 + 1) * 5 * 64 + lane) * 8;
  const unsigned short* wq2 = Wyp + ((size_t)(wid * 3 + 2) * 5 * 64 + lane) * 8;
  #pragma unroll
  for (int ks = 0; ks < 5; ++ks) {
    bf16x8 af  = *(const bf16x8*)(arow + ks * 32);
    bf16x8 w0f = *(const bf16x8*)(wq0 + ks * 512);
    bf16x8 w1f = *(const bf16x8*)(wq1 + ks * 512);
    bf16x8 w2f = *(const bf16x8*)(wq2 + ks * 512);
    acc0 = __builtin_amdgcn_mfma_f32_16x16x32_bf16(w0f, af, acc0, 0, 0, 0);
    acc1 = __builtin_amdgcn_mfma_f32_16x16x32_bf16(w1f, af, acc1, 0, 0, 0);
    acc2 = __builtin_amdgcn_mfma_f32_16x16x32_bf16(w2f, af, acc2, 0, 0, 0);
  }
  float a = attr[nbase + ch];
  float* yrow = y + (size_t)(nbase + ch) * 192 + quad * 4;
  { float4 st = {acc0[0]*a, acc0[1]*a, acc0[2]*a, acc0[3]*a};
    *(float4*)(yrow + (wid * 3 + 0) * 16) = st; }
  { float4 st = {acc1[0]*a, acc1[1]*a, acc1[2]*a, acc1[3]*a};
    *(float4*)(yrow + (wid * 3 + 1) * 16) = st; }
  { float4 st = {acc2[0]*a, acc2[1]*a, acc2[2]*a, acc2[3]*a};
    *(float4*)(yrow + (wid * 3 + 2) * 16) = st; }
}

// fused mid-stage: blocks [0,2500) = h_gemm, [2500,3125) = npre
__global__ __launch_bounds__(256) void k_midpre(
    const float* __restrict__ ed2b, const unsigned short* __restrict__ fc0p,
    unsigned short* __restrict__ hout,
    const float* __restrict__ xin, const float* __restrict__ attr,
    const unsigned short* __restrict__ Wyp, float* __restrict__ y) {
  __shared__ union ShU {
    WgemmShared w;
    unsigned short ash[16 * YSTR];
  } sh;
  if (blockIdx.x < 2500) {
    w_gemm_body(sh.w, blockIdx.x, ed2b, fc0p, hout);
  } else {
    npre_body(sh.ash, blockIdx.x - 2500, xin, attr, Wyp, y);
  }
}

// node_agg: r8 single-wave mapping (1 node/wave, grid 2500). THIS ROUND:
// the wbuf stream no longer exists — per 16-edge chunk, the wave RECOMPUTES
// w from h via the verified wtile MFMA pack (mrow=lane&15 = edge in chunk,
// K folded into fc1p) and stores it to wave-private LDS (stride 656 pad).
// The r0-proven 2-slot consume loop is unchanged except AB/Cw/DG read LDS
// (r10-verified read pattern, 0 bank conflicts). Removes 102 MB of HBM
// stream + its ~900cy/edge exposed latency.
#define EDST 656
__global__ __launch_bounds__(256) void node_agg(
    const float* __restrict__ y, const float* __restrict__ ed2a,
    const unsigned short* __restrict__ hbuf,
    const unsigned short* __restrict__ fc1p,
    const int* __restrict__ order, const int* __restrict__ obeg,
    const int* __restrict__ ocnt, unsigned short* __restrict__ aggb) {
  __shared__ __align__(16) char wls[4][16 * EDST];
  int tid = threadIdx.x, wid = tid >> 6, lane = tid & 63, l31 = lane & 31;
  int gw = blockIdx.x * 4 + wid;
  char* myw = &wls[wid][0];
  int mrow = lane & 15, quad = lane >> 4;
  // fixed per-lane byte offsets (loop-invariant)
  int voY  = 4 * lane;           // y scalar block
  int voX  = 256 + 16 * l31;     // y vector float4 {x0,x1,x2,0}
  int voAB = 4 * lane;           // w AB   (LDS)
  int voC  = 256 + 2 * lane;     // w C    (LDS)
  int voDG = 384 + 8 * l31;      // w DEFG (LDS)

#define E_LOAD(S, idx)                                                         \
  if ((idx) < cnt) {                                                           \
    const float4* ep = (const float4*)(ed2a + (size_t)(beg + (idx)) * 12);     \
    PE0##S = ep[0]; PE1##S = ep[1]; PE2##S = ep[2];                            \
  }
#define V_LOADL(S, li)                                                         \
  if ((li) < m) {                                                              \
    int srcn = __float_as_int(PE2##S.y);                                       \
    const char* yb = (const char*)y + (size_t)srcn * 768;                      \
    Y##S = *(const float*)(yb + voY);                                          \
    X##S = *(const f32x4*)(yb + voX);                                          \
    const char* wb = myw + (li) * EDST;                                        \
    AB##S = *(const unsigned*)(wb + voAB);                                     \
    Cw##S = *(const unsigned short*)(wb + voC);                                \
    DG##S = *(const uint2*)(wb + voDG);                                        \
  }
#define COMPUTE(S)                                                             \
  {                                                                            \
    float e0 = PE0##S.x, ey = PE0##S.y, ez = PE0##S.z, ex = PE0##S.w;          \
    float q0 = PE1##S.x, q1 = PE1##S.y, q2 = PE1##S.z, q3 = PE1##S.w;          \
    float q4 = PE2##S.x;                                                       \
    float Yv = Y##S, x0 = X##S.x, x1 = X##S.y, x2 = X##S.z;                    \
    float vA = bf2f(AB##S), vB = bfhi(AB##S), vC = bf2f(Cw##S);                \
    float vD = bf2f(DG##S.x), vE = bfhi(DG##S.x);                              \
    float vF = bf2f(DG##S.y), vG = bfhi(DG##S.y);                              \
    aK0 += Yv * e0 * vA;                                                       \
    float tB = Yv * vB; aK2x += tB * ey; aK2y += tB * ez; aK2z += tB * ex;     \
    float tC = Yv * vC;                                                        \
    aK5a += tC * q0; aK5b += tC * q1; aK5c += tC * q2;                         \
    aK5d += tC * q3; aK5e += tC * q4;                                          \
    float t1 = x0 * ey + x1 * ez + x2 * ex; aK1 += (RS3 * vE) * t1;            \
    float s3 = e0 * vD; aK3x += x0 * s3; aK3y += x1 * s3; aK3z += x2 * s3;     \
    float s4 = SQ3_ * vG;                                                      \
    aK4x += s4 * (B_ * (x2 * q0 + x1 * q1 - x0 * q4) - A_ * x0 * q2);          \
    aK4y += s4 * (B_ * (x0 * q1 + x2 * q3) + 2.f * A_ * x1 * q2);              \
    aK4z += s4 * (B_ * (x0 * q0 + x1 * q3 + x2 * q4) - A_ * x2 * q2);          \
    float s6 = SQ5_ * vF;                                                      \
    aK6a += s6 * (-B_ * (x0 * ex + x2 * ey));                                  \
    aK6b += s6 * (-B_ * (x0 * ez + x1 * ey));                                  \
    aK6c += s6 * ( A_ * (x0 * ey + x2 * ex - 2.f * x1 * ez));                  \
    aK6d += s6 * (-B_ * (x1 * ex + x2 * ez));                                  \
    aK6e += s6 * ( B_ * (x0 * ey - x2 * ex));                                  \
  }

  int n = order[gw], beg = obeg[gw], cnt = ocnt[gw];

  float aK0 = 0.f, aK2x = 0.f, aK2y = 0.f, aK2z = 0.f;
  float aK5a = 0.f, aK5b = 0.f, aK5c = 0.f, aK5d = 0.f, aK5e = 0.f;
  float aK1 = 0.f, aK3x = 0.f, aK3y = 0.f, aK3z = 0.f;
  float aK4x = 0.f, aK4y = 0.f, aK4z = 0.f;
  float aK6a = 0.f, aK6b = 0.f, aK6c = 0.f, aK6d = 0.f, aK6e = 0.f;

  float4 PE0a, PE1a, PE2a, PE0b, PE1b, PE2b;
  float Ya, Yb; f32x4 Xa, Xb;
  unsigned ABa, ABb; unsigned short Cwa, Cwb;
  uint2 DGa, DGb;

  for (int c0 = 0; c0 < cnt; c0 += 16) {
    // ---- fused w-GEMM for edges [c0, c0+16): verified pack code, LDS dest.
    // h-frag A-operand: mrow = edge in chunk (reads past cnt land in the
    // next node's h rows — valid memory, values never consumed).
    {
      const unsigned short* hb = hbuf + (size_t)(beg + c0 + mrow) * 64;
      bf16x8 a0 = *(const bf16x8*)(hb + quad * 8);
      bf16x8 a1 = *(const bf16x8*)(hb + 32 + quad * 8);
      char* wbase = myw + mrow * EDST;
      #pragma unroll
      for (int tt = 0; tt < 4; ++tt) {
        f32x4 Av = wtile(fc1p, a0, a1, mrow, quad, tt);
        f32x4 Bv = wtile(fc1p, a0, a1, mrow, quad, tt + 4);
        uint4 st;
        st.x = pack2bf(Av[0], Bv[0]);
        st.y = pack2bf(Av[1], Bv[1]);
        st.z = pack2bf(Av[2], Bv[2]);
        st.w = pack2bf(Av[3], Bv[3]);
        *(uint4*)(wbase + 64 * tt + 16 * quad) = st;
      }
      #pragma unroll
      for (int tt = 8; tt < 12; ++tt) {
        f32x4 Cv = wtile(fc1p, a0, a1, mrow, quad, tt);
        uint2 st;
        st.x = pack2bf(Cv[0], Cv[1]);
        st.y = pack2bf(Cv[2], Cv[3]);
        *(uint2*)(wbase + 256 + 32 * (tt - 8) + 8 * quad) = st;
      }
      #pragma unroll
      for (int tt = 12; tt < 14; ++tt) {
        f32x4 Dv = wtile(fc1p, a0, a1, mrow, quad, tt);
        f32x4 Ev = wtile(fc1p, a0, a1, mrow, quad, tt + 2);
        f32x4 Fv = wtile(fc1p, a0, a1, mrow, quad, tt + 4);
        f32x4 Gv = wtile(fc1p, a0, a1, mrow, quad, tt + 6);
        char* db = wbase + 384 + 128 * (tt - 12) + 32 * quad;
        uint4 s0, s1;
        s0.x = pack2bf(Dv[0], Ev[0]); s0.y = pack2bf(Fv[0], Gv[0]);
        s0.z = pack2bf(Dv[1], Ev[1]); s0.w = pack2bf(Fv[1], Gv[1]);
        s1.x = pack2bf(Dv[2], Ev[2]); s1.y = pack2bf(Fv[2], Gv[2]);
        s1.z = pack2bf(Dv[3], Ev[3]); s1.w = pack2bf(Fv[3], Gv[3]);
        *(uint4*)(db) = s0;
        *(uint4*)(db + 16) = s1;
      }
    }
    // ---- r0-proven 2-slot consume over this chunk ----
    int m = cnt - c0; if (m > 16) m = 16;
    E_LOAD(a, c0)
    E_LOAD(b, c0 + 1)
    V_LOADL(a, 0)
    int i = 0;
    while (i < m) {
      V_LOADL(b, i + 1)
      COMPUTE(a)
      E_LOAD(a, c0 + i + 2)
      ++i; if (i >= m) break;
      V_LOADL(a, i + 1)
      COMPUTE(b)
      E_LOAD(b, c0 + i + 2)
      ++i;
    }
  }

  // store accumulators (QDEG-scaled, bf16) to the node's agg row [960]
  unsigned short* ag = aggb + (size_t)n * 960;
  ag[lane]           = f2bf(aK0  * QDEG);
  ag[96 + 3 * lane]  = f2bf(aK2x * QDEG);
  ag[97 + 3 * lane]  = f2bf(aK2y * QDEG);
  ag[98 + 3 * lane]  = f2bf(aK2z * QDEG);
  ag[480 + 5 * lane] = f2bf(aK5a * QDEG);
  ag[481 + 5 * lane] = f2bf(aK5b * QDEG);
  ag[482 + 5 * lane] = f2bf(aK5c * QDEG);
  ag[483 + 5 * lane] = f2bf(aK5d * QDEG);
  ag[484 + 5 * lane] = f2bf(aK5e * QDEG);
  if (lane < 32) {
    ag[64 + lane]      = f2bf(aK1  * QDEG);
    ag[288 + 3 * lane] = f2bf(aK3x * QDEG);
    ag[289 + 3 * lane] = f2bf(aK3y * QDEG);
    ag[290 + 3 * lane] = f2bf(aK3z * QDEG);
    ag[384 + 3 * lane] = f2bf(aK4x * QDEG);
    ag[385 + 3 * lane] = f2bf(aK4y * QDEG);
    ag[386 + 3 * lane] = f2bf(aK4z * QDEG);
    ag[800 + 5 * lane] = f2bf(aK6a * QDEG);
    ag[801 + 5 * lane] = f2bf(aK6b * QDEG);
    ag[802 + 5 * lane] = f2bf(aK6c * QDEG);
    ag[803 + 5 * lane] = f2bf(aK6d * QDEG);
    ag[804 + 5 * lane] = f2bf(aK6e * QDEG);
  }
#undef E_LOAD
#undef V_LOADL
#undef COMPUTE
}

// k_out (MFMA): out[n,0:320] = attr[n] * (A[n,0:1120] @ W).
#define ASTR 1128
__global__ __launch_bounds__(256) void k_out(
    const unsigned short* __restrict__ aggb, const float* __restrict__ xin,
    const float* __restrict__ attr, const unsigned short* __restrict__ Wp,
    float* __restrict__ out) {
  __shared__ __align__(16) unsigned short Ash[16 * ASTR];
  int t = threadIdx.x;
  int nbase = blockIdx.x * 16;
  for (int idx = t; idx < 16 * 480; idx += 256) {
    int row = idx / 480, c = idx - row * 480;
    *(unsigned*)(Ash + row * ASTR + 2 * c) =
        *(const unsigned*)(aggb + (size_t)(nbase + row) * 960 + 2 * c);
  }
  for (int idx = t; idx < 16 * 80; idx += 256) {
    int row = idx / 80, c = idx - row * 80;
    const float* xp = xin + (size_t)(nbase + row) * 160 + 2 * c;
    *(unsigned*)(Ash + row * ASTR + 960 + 2 * c) = pack2bf(xp[0], xp[1]);
  }
  __syncthreads();

  int wid = t >> 6, lane = t & 63;
  int ch = lane & 15, quad = lane >> 4;
  f32x4 acc0 = {0.f,0.f,0.f,0.f}, acc1 = {0.f,0.f,0.f,0.f};
  f32x4 acc2 = {0.f,0.f,0.f,0.f}, acc3 = {0.f,0.f,0.f,0.f};
  f32x4 acc4 = {0.f,0.f,0.f,0.f};
  const unsigned short* arow = Ash + ch * ASTR + quad * 8;
  const unsigned short* wq0 = Wp + ((size_t)(wid * 5 + 0) * 35 * 64 + lane) * 8;
  const unsigned short* wq1 = Wp + ((size_t)(wid * 5 + 1) * 35 * 64 + lane) * 8;
  const unsigned short* wq2 = Wp + ((size_t)(wid * 5 + 2) * 35 * 64 + lane) * 8;
  const unsigned short* wq3 = Wp + ((size_t)(wid * 5 + 3) * 35 * 64 + lane) * 8;
  const unsigned short* wq4 = Wp + ((size_t)(wid * 5 + 4) * 35 * 64 + lane) * 8;
  for (int ks = 0; ks < 35; ++ks) {
    bf16x8 af = *(const bf16x8*)(arow + ks * 32);
    bf16x8 w0f = *(const bf16x8*)(wq0 + ks * 512);
    bf16x8 w1f = *(const bf16x8*)(wq1 + ks * 512);
    bf16x8 w2f = *(const bf16x8*)(wq2 + ks * 512);
    bf16x8 w3f = *(const bf16x8*)(wq3 + ks * 512);
    bf16x8 w4f = *(const bf16x8*)(wq4 + ks * 512);
    acc0 = __builtin_amdgcn_mfma_f32_16x16x32_bf16(w0f, af, acc0, 0, 0, 0);
    acc1 = __builtin_amdgcn_mfma_f32_16x16x32_bf16(w1f, af, acc1, 0, 0, 0);
    acc2 = __builtin_amdgcn_mfma_f32_16x16x32_bf16(w2f, af, acc2, 0, 0, 0);
    acc3 = __builtin_amdgcn_mfma_f32_16x16x32_bf16(w3f, af, acc3, 0, 0, 0);
    acc4 = __builtin_amdgcn_mfma_f32_16x16x32_bf16(w4f, af, acc4, 0, 0, 0);
  }
  float a = attr[nbase + ch];
  float* orow = out + (size_t)(nbase + ch) * 320 + quad * 4;
  {
    float4 st = {acc0[0]*a, acc0[1]*a, acc0[2]*a, acc0[3]*a};
    *(float4*)(orow + (wid * 5 + 0) * 16) = st;
  }
  {
    float4 st = {acc1[0]*a, acc1[1]*a, acc1[2]*a, acc1[3]*a};
    *(float4*)(orow + (wid * 5 + 1) * 16) = st;
  }
  {
    float4 st = {acc2[0]*a, acc2[1]*a, acc2[2]*a, acc2[3]*a};
    *(float4*)(orow + (wid * 5 + 2) * 16) = st;
  }
  {
    float4 st = {acc3[0]*a, acc3[1]*a, acc3[2]*a, acc3[3]*a};
    *(float4*)(orow + (wid * 5 + 3) * 16) = st;
  }
  {
    float4 st = {acc4[0]*a, acc4[1]*a, acc4[2]*a, acc4[3]*a};
    *(float4*)(orow + (wid * 5 + 4) * 16) = st;
  }
}

extern "C" void kernel_launch(void* const* d_in, const int* in_sizes, int n_in,
                              void* d_out, int out_size, void* d_ws, size_t ws_size,
                              hipStream_t stream) {
  const float* node_input = (const float*)d_in[0];
  const float* node_attr  = (const float*)d_in[1];
  const int*   edge_src   = (const int*)d_in[2];
  const int*   edge_dst   = (const int*)d_in[3];
  const float* edge_attr  = (const float*)d_in[4];
  const float* ele        = (const float*)d_in[5];
  const float* sc_w0      = (const float*)d_in[6];
  const float* sc_w1      = (const float*)d_in[7];
  const float* l1_w0      = (const float*)d_in[8];
  const float* l1_w1      = (const float*)d_in[9];
  const float* fc_w0      = (const float*)d_in[10];
  const float* fc_w1      = (const float*)d_in[11];
  const float* l2_w0      = (const float*)d_in[12];
  const float* l2_w1      = (const float*)d_in[13];
  const float* l2_w2      = (const float*)d_in[14];
  float* out = (float*)d_out;

  char* base = (char*)d_ws;
  float* y              = (float*)(base);                       // 7.68 MB (stride 192)
  unsigned short* hbuf  = (unsigned short*)(base + 7680000);    // 20.5 MB (128 B/edge)
  float* ed2a           = (float*)(base + 110080000);           // 7.68 MB (stride 12)
  float* ed2b           = (float*)(base + 117760000);           // 5.12 MB (stride 8)
  int* counts           = (int*)(base + 122880000);
  int* offs             = (int*)(base + 122920000);
  int* cur              = (int*)(base + 122960000);
  int* order            = (int*)(base + 123000000);
  int* obeg             = (int*)(base + 123040000);
  int* ocnt             = (int*)(base + 123080000);
  int* dcur             = (int*)(base + 123120000);             // 1 KB
  unsigned short* fc1p  = (unsigned short*)(base + 123121024);  // 40 KB
  unsigned short* aggb  = (unsigned short*)(base + 123162624);  // 19.2 MB
  unsigned short* Wp    = (unsigned short*)(base + 142362624);  // 716.8 KB
  unsigned short* Wyp   = (unsigned short*)(base + 143079424);  // 61.4 KB
  unsigned short* fc0p  = (unsigned short*)(base + 143140864);  // 4 KB

  hipMemsetAsync(counts, 0, N_NODES * sizeof(int), stream);
  hipLaunchKernelGGL(k_prep, dim3(2233), dim3(256), 0, stream,
                     edge_dst, counts, fc_w1, fc1p, fc_w0, fc0p,
                     sc_w0, sc_w1, l2_w0, l2_w1, l2_w2, l1_w0, l1_w1, Wp, Wyp);
  hipLaunchKernelGGL(k_scan, dim3(1), dim3(256), 0, stream, counts, offs, cur, dcur);
  hipLaunchKernelGGL(k_perm, dim3(N_EDGES / 256), dim3(256), 0, stream,
                     edge_dst, cur, counts, offs, dcur, order, obeg, ocnt,
                     ele, edge_attr, edge_src, ed2a, ed2b);
  hipLaunchKernelGGL(k_midpre, dim3(3125), dim3(256), 0, stream,
                     ed2b, fc0p, hbuf, node_input, node_attr, Wyp, y);
  hipLaunchKernelGGL(node_agg, dim3(2500), dim3(256), 0, stream,
                     y, ed2a, hbuf, fc1p, order, obeg, ocnt, aggb);
  hipLaunchKernelGGL(k_out, dim3(625), dim3(256), 0, stream,
                     aggb, node_input, node_attr, Wp, out);
}

// Round 12
// 219.451 us; speedup vs baseline: 1.2412x; 1.2412x over previous
//
#include <hip/hip_runtime.h>
#include <cstddef>
#include <cstdint>

#define N_NODES 10000
#define N_EDGES 160000

// ---- constants ----
#define RS8    0.35355339059327373f   // 1/sqrt(8)
#define RS32   0.17677669529663687f   // 1/sqrt(32)
#define RS96   0.10206207261596575f   // 1/sqrt(96)
#define RS128  0.08838834764831845f   // 1/sqrt(128)
#define RS3    0.5773502691896258f    // 1/sqrt(3)
#define SQ3_   1.7320508075688772f
#define SQ5_   2.23606797749979f
#define A_     0.18257418583505536f   // 1/sqrt(30)
#define B_     0.31622776601683794f   // 1/sqrt(10)
#define SILU_C_ 1.6765208f
#define CS_    0.3826834323650898f    // sin(pi/8)
#define CX_    0.9238795325112867f    // cos(pi/8)
#define QDEG   0.25f                  // 1/sqrt(16)

typedef __attribute__((ext_vector_type(8))) short bf16x8;
typedef __attribute__((ext_vector_type(4))) float f32x4;
typedef __attribute__((ext_vector_type(2))) unsigned u32x2;
typedef __attribute__((ext_vector_type(4))) unsigned u32x4;

__device__ inline float bf2f(unsigned v) {
  union { unsigned u; float f; } c; c.u = v << 16; return c.f;
}
__device__ inline float bfhi(unsigned v) {   // float from HIGH 16 bits
  union { unsigned u; float f; } c; c.u = v & 0xffff0000u; return c.f;
}
__device__ inline unsigned short f2bf(float f) {
  union { float f; unsigned u; } c; c.f = f;
  unsigned r = c.u + 0x7fff + ((c.u >> 16) & 1);
  return (unsigned short)(r >> 16);
}
__device__ inline unsigned pack2bf(float a, float b) {
  return (unsigned)f2bf(a) | ((unsigned)f2bf(b) << 16);
}
__device__ inline float silu_c(float x) {
  return SILU_C_ * x / (1.f + __expf(-x));
}

// k_prep: fused (counts pre-zeroed by hipMemsetAsync):
//  blocks [0,625)     : edge-dst histogram (atomics)
//  blocks [625,713)   : fc1p + fc0p packs
//  blocks [713,2233)  : Wp[1120][320] + Wyp[160][192] (verified MFMA
//                       first-operand fragment order, scales folded)
__global__ __launch_bounds__(256) void k_prep(
    const int* __restrict__ edst, int* __restrict__ counts,
    const float* __restrict__ fc1, unsigned short* __restrict__ fc1p,
    const float* __restrict__ fc0, unsigned short* __restrict__ fc0p,
    const float* __restrict__ sc_w0, const float* __restrict__ sc_w1,
    const float* __restrict__ w0, const float* __restrict__ w1,
    const float* __restrict__ w2, const float* __restrict__ l1_w0,
    const float* __restrict__ l1_w1, unsigned short* __restrict__ Wp,
    unsigned short* __restrict__ Wyp) {
  int b = blockIdx.x, t = threadIdx.x;
  if (b < 625) {
    int e = b * 256 + t;
    if (e < N_EDGES) atomicAdd(&counts[edst[e]], 1);
    return;
  }
  if (b < 713) {
    int i = (b - 625) * 256 + t;
    if (i < 20480) {
      int j = i & 7, q = (i >> 3) & 3, n = (i >> 5) & 15, kq = (i >> 9) & 1, tt = i >> 10;
      int k = kq * 32 + q * 8 + j;
      fc1p[i] = f2bf(fc1[k * 320 + tt * 16 + n]);
    } else if (i < 22528) {
      int ii = i - 20480;
      int j = ii & 7;
      int lane = (ii >> 3) & 63;
      int ch = lane & 15, quad = lane >> 4;
      int nt = ii >> 9;                  // [0,4)
      int k = quad * 8 + j;
      float v = (k < 8) ? RS8 * fc0[k * 64 + nt * 16 + ch] : 0.f;
      fc0p[ii] = f2bf(v);
    }
    return;
  }
  int i = (b - 713) * 256 + t;
  if (i < 358400) {
    int j = i & 7;
    int lane = (i >> 3) & 63;
    int ch = lane & 15, quad = lane >> 4;
    int r = i >> 9;                    // [0,700)
    int nt = r / 35, ks = r - nt * 35;
    int k = ks * 32 + quad * 8 + j;
    int oc = nt * 16 + ch;
    float v = 0.f;
    if (k < 96) {                                   // m0 -> oc [0,64)
      if (oc < 64) v = (CX_ * RS96) * w0[k * 64 + oc];
    } else if (k < 480) {                           // m1 -> oc [64,160)
      int tt = k - 96, u = tt / 3, ii = tt - u * 3;
      if (oc >= 64 && oc < 160) {
        int d = oc - 64, vv = d / 3, jj = d - vv * 3;
        if (jj == ii) v = (CX_ * RS128) * w1[u * 32 + vv];
      }
    } else if (k < 960) {                           // m2 -> oc [160,320)
      int tt = k - 480, u = tt / 5, kk = tt - u * 5;
      if (oc >= 160) {
        int d = oc - 160, vv = d / 5, jj = d - vv * 5;
        if (jj == kk) v = RS96 * w2[u * 32 + vv];
      }
    } else if (k < 1024) {                          // x0 sc -> oc [0,64)
      int u = k - 960;
      if (oc < 64) v = (CS_ * 0.125f) * sc_w0[u * 64 + oc];
    } else {                                        // x1 sc -> oc [64,160)
      int tt = k - 1024, u = tt / 3, ii = tt - u * 3;
      if (oc >= 64 && oc < 160) {
        int d = oc - 64, vv = d / 3, jj = d - vv * 3;
        if (jj == ii) v = (CS_ * RS32) * sc_w1[u * 32 + vv];
      }
    }
    Wp[i] = f2bf(v);
  } else if (i < 358400 + 30720) {
    // Wyp: y[n, 0:192] = attr * (x[n,0:160] @ Wy). KS=5, NT=12.
    int ii2 = i - 358400;
    int j = ii2 & 7;
    int lane = (ii2 >> 3) & 63;
    int ch = lane & 15, quad = lane >> 4;
    int r = ii2 >> 9;                  // [0,60)
    int nt = r / 5, ks = r - nt * 5;
    int k = ks * 32 + quad * 8 + j;    // [0,160)
    int oc = nt * 16 + ch;             // [0,192)
    float v = 0.f;
    if (k < 64) {
      if (oc < 64) v = 0.125f * l1_w0[k * 64 + oc];
    } else {
      int tt = k - 64, u = tt / 3, ci = tt - u * 3;   // u<32, ci<3
      if (oc >= 64) {
        int d = oc - 64, vv = d >> 2, jj = d & 3;
        if (jj == ci) v = RS32 * l1_w1[u * 32 + vv];  // jj==3 never matches
      }
    }
    Wyp[ii2] = f2bf(v);
  }
}

// exclusive scan of counts -> offs/cur; degree histogram + descending-degree
// exclusive scan -> dcur (single block).
__global__ __launch_bounds__(256) void k_scan(const int* __restrict__ counts,
                                              int* __restrict__ offs,
                                              int* __restrict__ cur,
                                              int* __restrict__ dcur) {
  __shared__ int ps[256];
  __shared__ int dbin[256];
  int t = threadIdx.x;
  dbin[t] = 0;
  int base = t * 40;
  int sum = 0;
  for (int i = 0; i < 40; ++i) {
    int idx = base + i;
    if (idx < N_NODES) sum += counts[idx];
  }
  ps[t] = sum;
  __syncthreads();
  for (int off = 1; off < 256; off <<= 1) {
    int v = (t >= off) ? ps[t - off] : 0;
    __syncthreads();
    ps[t] += v;
    __syncthreads();
  }
  int run = (t == 0) ? 0 : ps[t - 1];
  for (int i = 0; i < 40; ++i) {
    int idx = base + i;
    if (idx < N_NODES) {
      int c = counts[idx];
      offs[idx] = run; cur[idx] = run;
      run += c;
      atomicAdd(&dbin[c < 255 ? c : 255], 1);
    }
  }
  __syncthreads();
  int rb = 255 - t;
  int v = dbin[rb];
  __syncthreads();
  ps[t] = v;
  __syncthreads();
  for (int off = 1; off < 256; off <<= 1) {
    int u = (t >= off) ? ps[t - off] : 0;
    __syncthreads();
    ps[t] += u;
    __syncthreads();
  }
  dcur[rb] = ps[t] - v;
}

// Permute kernel: scatter-write ed2a (stride 12 f: SH+src) and ed2b
// (stride 8 f: ele); node scatter (degree-desc rank -> order/obeg/ocnt).
__global__ __launch_bounds__(256) void k_perm(
    const int* __restrict__ edst, int* __restrict__ cur,
    const int* __restrict__ counts, const int* __restrict__ offs,
    int* __restrict__ dcur, int* __restrict__ order,
    int* __restrict__ obeg, int* __restrict__ ocnt,
    const float* __restrict__ ele, const float* __restrict__ eattr,
    const int* __restrict__ esrc, float* __restrict__ ed2a,
    float* __restrict__ ed2b) {
  __shared__ __align__(16) float sh_ea[256 * 9];
  __shared__ __align__(16) float sh_el[256 * 8];
  int t = threadIdx.x;
  int eb = blockIdx.x * 256;
  int e = eb + t;
  for (int i = t; i < 2304; i += 256) sh_ea[i] = eattr[(size_t)eb * 9 + i];
  {
    const float4* src = (const float4*)(ele + (size_t)eb * 8);
    float4* dst = (float4*)sh_el;
    dst[t] = src[t]; dst[t + 256] = src[t + 256];
  }
  __syncthreads();
  int d = edst[e];
  int p = atomicAdd(&cur[d], 1);
  const float* ea = sh_ea + t * 9;
  const float* el = sh_el + t * 8;
  float4 r0 = {ea[0], ea[1], ea[2], ea[3]};
  float4 r1 = {ea[4], ea[5], ea[6], ea[7]};
  float4 r2 = {ea[8], __int_as_float(esrc[e]), 0.f, 0.f};
  float4* da = (float4*)(ed2a + (size_t)p * 12);
  da[0] = r0; da[1] = r1; da[2] = r2;
  float4 r3 = {el[0], el[1], el[2], el[3]};
  float4 r4 = {el[4], el[5], el[6], el[7]};
  float4* db = (float4*)(ed2b + (size_t)p * 8);
  db[0] = r3; db[1] = r4;
  if (e < N_NODES) {
    int c = counts[e];
    int b = c < 255 ? c : 255;
    int q = atomicAdd(&dcur[b], 1);
    order[q] = e; obeg[q] = offs[e]; ocnt[q] = c;
  }
}

__device__ inline f32x4 wtile(const unsigned short* __restrict__ fc1p,
                              bf16x8 a0, bf16x8 a1, int mrow, int quad, int t) {
  f32x4 acc = {0.f, 0.f, 0.f, 0.f};
  bf16x8 b0 = *(const bf16x8*)(fc1p + ((size_t)((t * 2 + 0) * 16 + mrow) * 4 + quad) * 8);
  bf16x8 b1 = *(const bf16x8*)(fc1p + ((size_t)((t * 2 + 1) * 16 + mrow) * 4 + quad) * 8);
  acc = __builtin_amdgcn_mfma_f32_16x16x32_bf16(b0, a0, acc, 0, 0, 0);
  acc = __builtin_amdgcn_mfma_f32_16x16x32_bf16(b1, a1, acc, 0, 0, 0);
  return acc;
}

struct WgemmShared {
  __align__(16) unsigned short elb[64 * 32];   // 4KB: ele bf16, K padded 8->32
  __align__(16) unsigned short h[64 * 72];     // 9KB, 72-stride pad
};

// STREAMING MFMA radial GEMM: 64 edges/block, reads ele from ed2b
// (sequential, stride 8 f). h-phase MFMA (verified r7); pack-phase writes
// packed wbuf (640 B/edge) with NON-TEMPORAL stores (write-once, 102 MB >>
// L2 — avoid thrashing L2 during k_midpre).
__device__ void w_gemm_body(WgemmShared& sh, int blk,
    const float* __restrict__ ed2b, const unsigned short* __restrict__ fc0p,
    const unsigned short* __restrict__ fc1p, unsigned short* __restrict__ wout) {
  int t = threadIdx.x;
  int eb = blk * 64;
  {
    int e = t >> 2, q = t & 3;
    uint4 pk = {0u, 0u, 0u, 0u};
    if (q == 0) {
      const float4* ep = (const float4*)(ed2b + (size_t)(eb + e) * 8);
      float4 u = ep[0], v = ep[1];
      pk.x = pack2bf(u.x, u.y); pk.y = pack2bf(u.z, u.w);
      pk.z = pack2bf(v.x, v.y); pk.w = pack2bf(v.z, v.w);
    }
    *(uint4*)(sh.elb + e * 32 + q * 8) = pk;
  }
  __syncthreads();

  int wv = t >> 6, lane = t & 63;
  int ch16 = lane & 15, quad = lane >> 4;
  {
    bf16x8 af = *(const bf16x8*)(sh.elb + (wv * 16 + ch16) * 32 + quad * 8);
    bf16x8 b0 = *(const bf16x8*)(fc0p + 0 * 512 + lane * 8);
    bf16x8 b1 = *(const bf16x8*)(fc0p + 1 * 512 + lane * 8);
    bf16x8 b2 = *(const bf16x8*)(fc0p + 2 * 512 + lane * 8);
    bf16x8 b3 = *(const bf16x8*)(fc0p + 3 * 512 + lane * 8);
    f32x4 z = {0.f, 0.f, 0.f, 0.f};
    f32x4 h0 = __builtin_amdgcn_mfma_f32_16x16x32_bf16(b0, af, z, 0, 0, 0);
    f32x4 h1 = __builtin_amdgcn_mfma_f32_16x16x32_bf16(b1, af, z, 0, 0, 0);
    f32x4 h2 = __builtin_amdgcn_mfma_f32_16x16x32_bf16(b2, af, z, 0, 0, 0);
    f32x4 h3 = __builtin_amdgcn_mfma_f32_16x16x32_bf16(b3, af, z, 0, 0, 0);
    unsigned short* hb = sh.h + (wv * 16 + ch16) * 72 + quad * 4;
    uint2 s;
    s.x = pack2bf(silu_c(h0[0]), silu_c(h0[1]));
    s.y = pack2bf(silu_c(h0[2]), silu_c(h0[3]));
    *(uint2*)(hb + 0) = s;
    s.x = pack2bf(silu_c(h1[0]), silu_c(h1[1]));
    s.y = pack2bf(silu_c(h1[2]), silu_c(h1[3]));
    *(uint2*)(hb + 16) = s;
    s.x = pack2bf(silu_c(h2[0]), silu_c(h2[1]));
    s.y = pack2bf(silu_c(h2[2]), silu_c(h2[3]));
    *(uint2*)(hb + 32) = s;
    s.x = pack2bf(silu_c(h3[0]), silu_c(h3[1]));
    s.y = pack2bf(silu_c(h3[2]), silu_c(h3[3]));
    *(uint2*)(hb + 48) = s;
  }
  __syncthreads();

  int m0 = wv * 16;
  int mrow = lane & 15;
  bf16x8 a0 = *(const bf16x8*)(sh.h + (m0 + mrow) * 72 + quad * 8);
  bf16x8 a1 = *(const bf16x8*)(sh.h + (m0 + mrow) * 72 + 32 + quad * 8);
  char* wbase = (char*)wout + (size_t)(eb + m0 + mrow) * 640;
  const float K = 0.125f;
  #pragma unroll
  for (int tt = 0; tt < 4; ++tt) {
    f32x4 Av = wtile(fc1p, a0, a1, mrow, quad, tt);
    f32x4 Bv = wtile(fc1p, a0, a1, mrow, quad, tt + 4);
    u32x4 st;
    st.x = pack2bf(Av[0] * K, Bv[0] * K);
    st.y = pack2bf(Av[1] * K, Bv[1] * K);
    st.z = pack2bf(Av[2] * K, Bv[2] * K);
    st.w = pack2bf(Av[3] * K, Bv[3] * K);
    __builtin_nontemporal_store(st, (u32x4*)(wbase + 64 * tt + 16 * quad));
  }
  #pragma unroll
  for (int tt = 8; tt < 12; ++tt) {
    f32x4 Cv = wtile(fc1p, a0, a1, mrow, quad, tt);
    u32x2 st;
    st.x = pack2bf(Cv[0] * K, Cv[1] * K);
    st.y = pack2bf(Cv[2] * K, Cv[3] * K);
    __builtin_nontemporal_store(st, (u32x2*)(wbase + 256 + 32 * (tt - 8) + 8 * quad));
  }
  #pragma unroll
  for (int tt = 12; tt < 14; ++tt) {
    f32x4 Dv = wtile(fc1p, a0, a1, mrow, quad, tt);
    f32x4 Ev = wtile(fc1p, a0, a1, mrow, quad, tt + 2);
    f32x4 Fv = wtile(fc1p, a0, a1, mrow, quad, tt + 4);
    f32x4 Gv = wtile(fc1p, a0, a1, mrow, quad, tt + 6);
    char* db = wbase + 384 + 128 * (tt - 12) + 32 * quad;
    u32x4 s0, s1;
    s0.x = pack2bf(Dv[0] * K, Ev[0] * K); s0.y = pack2bf(Fv[0] * K, Gv[0] * K);
    s0.z = pack2bf(Dv[1] * K, Ev[1] * K); s0.w = pack2bf(Fv[1] * K, Gv[1] * K);
    s1.x = pack2bf(Dv[2] * K, Ev[2] * K); s1.y = pack2bf(Fv[2] * K, Gv[2] * K);
    s1.z = pack2bf(Dv[3] * K, Ev[3] * K); s1.w = pack2bf(Fv[3] * K, Gv[3] * K);
    __builtin_nontemporal_store(s0, (u32x4*)(db));
    __builtin_nontemporal_store(s1, (u32x4*)(db + 16));
  }
}

// k_npre body (MFMA): y[n, 0:192] = attr[n] * (bf16(xin[n,0:160]) @ Wyp).
#define YSTR 168
__device__ void npre_body(unsigned short* Ash, int blk,
    const float* __restrict__ xin, const float* __restrict__ attr,
    const unsigned short* __restrict__ Wyp, float* __restrict__ y) {
  int t = threadIdx.x;
  int nbase = blk * 16;
  for (int idx = t; idx < 16 * 80; idx += 256) {
    int row = idx / 80, c = idx - row * 80;
    const float* xp = xin + (size_t)(nbase + row) * 160 + 2 * c;
    *(unsigned*)(Ash + row * YSTR + 2 * c) = pack2bf(xp[0], xp[1]);
  }
  __syncthreads();
  int wid = t >> 6, lane = t & 63;
  int ch = lane & 15, quad = lane >> 4;
  const unsigned short* arow = Ash + ch * YSTR + quad * 8;
  f32x4 acc0 = {0.f,0.f,0.f,0.f}, acc1 = {0.f,0.f,0.f,0.f}, acc2 = {0.f,0.f,0.f,0.f};
  const unsigned short* wq0 = Wyp + ((size_t)(wid * 3 + 0) * 5 * 64 + lane) * 8;
  const unsigned short* wq1 = Wyp + ((size_t)(wid * 3 + 1) * 5 * 64 + lane) * 8;
  const unsigned short* wq2 = Wyp + ((size_t)(wid * 3 + 2) * 5 * 64 + lane) * 8;
  #pragma unroll
  for (int ks = 0; ks < 5; ++ks) {
    bf16x8 af  = *(const bf16x8*)(arow + ks * 32);
    bf16x8 w0f = *(const bf16x8*)(wq0 + ks * 512);
    bf16x8 w1f = *(const bf16x8*)(wq1 + ks * 512);
    bf16x8 w2f = *(const bf16x8*)(wq2 + ks * 512);
    acc0 = __builtin_amdgcn_mfma_f32_16x16x32_bf16(w0f, af, acc0, 0, 0, 0);
    acc1 = __builtin_amdgcn_mfma_f32_16x16x32_bf16(w1f, af, acc1, 0, 0, 0);
    acc2 = __builtin_amdgcn_mfma_f32_16x16x32_bf16(w2f, af, acc2, 0, 0, 0);
  }
  float a = attr[nbase + ch];
  float* yrow = y + (size_t)(nbase + ch) * 192 + quad * 4;
  { float4 st = {acc0[0]*a, acc0[1]*a, acc0[2]*a, acc0[3]*a};
    *(float4*)(yrow + (wid * 3 + 0) * 16) = st; }
  { float4 st = {acc1[0]*a, acc1[1]*a, acc1[2]*a, acc1[3]*a};
    *(float4*)(yrow + (wid * 3 + 1) * 16) = st; }
  { float4 st = {acc2[0]*a, acc2[1]*a, acc2[2]*a, acc2[3]*a};
    *(float4*)(yrow + (wid * 3 + 2) * 16) = st; }
}

// fused mid-stage: blocks [0,2500) = w_gemm, [2500,3125) = npre
__global__ __launch_bounds__(256) void k_midpre(
    const float* __restrict__ ed2b, const unsigned short* __restrict__ fc0p,
    const unsigned short* __restrict__ fc1p, unsigned short* __restrict__ wout,
    const float* __restrict__ xin, const float* __restrict__ attr,
    const unsigned short* __restrict__ Wyp, float* __restrict__ y) {
  __shared__ union ShU {
    WgemmShared w;
    unsigned short ash[16 * YSTR];
  } sh;
  if (blockIdx.x < 2500) {
    w_gemm_body(sh.w, blockIdx.x, ed2b, fc0p, fc1p, wout);
  } else {
    npre_body(sh.ash, blockIdx.x - 2500, xin, attr, Wyp, y);
  }
}

// node_agg: r8-proven structure (1 node/wave, grid 2500, round-0 2-slot
// loop, no LDS) with ONE cache-policy change: the wbuf loads (read-once
// 102 MB stream) are NON-TEMPORAL so they stop evicting the 7.7 MB y table
// from L2 — y's srcn-gather is the only load covered by just ~1 iteration,
// so its hit rate is the exposed latency. Instruction structure unchanged.
__global__ __launch_bounds__(256) void node_agg(
    const float* __restrict__ y, const float* __restrict__ ed2a,
    const unsigned short* __restrict__ wbuf,
    const int* __restrict__ order, const int* __restrict__ obeg,
    const int* __restrict__ ocnt, unsigned short* __restrict__ aggb) {
  int tid = threadIdx.x, wid = tid >> 6, lane = tid & 63, l31 = lane & 31;
  int gw = blockIdx.x * 4 + wid;
  // fixed per-lane byte offsets (loop-invariant)
  int voY  = 4 * lane;           // y scalar block
  int voX  = 256 + 16 * l31;     // y vector float4 {x0,x1,x2,0}
  int voAB = 4 * lane;           // wbuf AB
  int voC  = 256 + 2 * lane;     // wbuf C
  int voDG = 384 + 8 * l31;      // wbuf DEFG

#define E_LOAD(S, idx)                                                         \
  if ((idx) < cnt) {                                                           \
    const float4* ep = (const float4*)(ed2a + (size_t)(beg + (idx)) * 12);     \
    PE0##S = ep[0]; PE1##S = ep[1]; PE2##S = ep[2];                            \
  }
#define V_LOAD(S, idx)                                                         \
  if ((idx) < cnt) {                                                           \
    int srcn = __float_as_int(PE2##S.y);                                       \
    const char* yb = (const char*)y + (size_t)srcn * 768;                      \
    Y##S = *(const float*)(yb + voY);                                          \
    X##S = *(const f32x4*)(yb + voX);                                          \
    const char* wb = (const char*)wbuf + (size_t)(beg + (idx)) * 640;          \
    AB##S = __builtin_nontemporal_load((const unsigned*)(wb + voAB));          \
    Cw##S = __builtin_nontemporal_load((const unsigned short*)(wb + voC));     \
    DG##S = __builtin_nontemporal_load((const u32x2*)(wb + voDG));             \
  }
#define COMPUTE(S)                                                             \
  {                                                                            \
    float e0 = PE0##S.x, ey = PE0##S.y, ez = PE0##S.z, ex = PE0##S.w;          \
    float q0 = PE1##S.x, q1 = PE1##S.y, q2 = PE1##S.z, q3 = PE1##S.w;          \
    float q4 = PE2##S.x;                                                       \
    float Yv = Y##S, x0 = X##S.x, x1 = X##S.y, x2 = X##S.z;                    \
    float vA = bf2f(AB##S), vB = bfhi(AB##S), vC = bf2f(Cw##S);                \
    float vD = bf2f(DG##S.x), vE = bfhi(DG##S.x);                              \
    float vF = bf2f(DG##S.y), vG = bfhi(DG##S.y);                              \
    aK0 += Yv * e0 * vA;                                                       \
    float tB = Yv * vB; aK2x += tB * ey; aK2y += tB * ez; aK2z += tB * ex;     \
    float tC = Yv * vC;                                                        \
    aK5a += tC * q0; aK5b += tC * q1; aK5c += tC * q2;                         \
    aK5d += tC * q3; aK5e += tC * q4;                                          \
    float t1 = x0 * ey + x1 * ez + x2 * ex; aK1 += (RS3 * vE) * t1;            \
    float s3 = e0 * vD; aK3x += x0 * s3; aK3y += x1 * s3; aK3z += x2 * s3;     \
    float s4 = SQ3_ * vG;                                                      \
    aK4x += s4 * (B_ * (x2 * q0 + x1 * q1 - x0 * q4) - A_ * x0 * q2);          \
    aK4y += s4 * (B_ * (x0 * q1 + x2 * q3) + 2.f * A_ * x1 * q2);              \
    aK4z += s4 * (B_ * (x0 * q0 + x1 * q3 + x2 * q4) - A_ * x2 * q2);          \
    float s6 = SQ5_ * vF;                                                      \
    aK6a += s6 * (-B_ * (x0 * ex + x2 * ey));                                  \
    aK6b += s6 * (-B_ * (x0 * ez + x1 * ey));                                  \
    aK6c += s6 * ( A_ * (x0 * ey + x2 * ex - 2.f * x1 * ez));                  \
    aK6d += s6 * (-B_ * (x1 * ex + x2 * ez));                                  \
    aK6e += s6 * ( B_ * (x0 * ey - x2 * ex));                                  \
  }

  int n = order[gw], beg = obeg[gw], cnt = ocnt[gw];

  float aK0 = 0.f, aK2x = 0.f, aK2y = 0.f, aK2z = 0.f;
  float aK5a = 0.f, aK5b = 0.f, aK5c = 0.f, aK5d = 0.f, aK5e = 0.f;
  float aK1 = 0.f, aK3x = 0.f, aK3y = 0.f, aK3z = 0.f;
  float aK4x = 0.f, aK4y = 0.f, aK4z = 0.f;
  float aK6a = 0.f, aK6b = 0.f, aK6c = 0.f, aK6d = 0.f, aK6e = 0.f;

  float4 PE0a, PE1a, PE2a, PE0b, PE1b, PE2b;
  float Ya, Yb; f32x4 Xa, Xb;
  unsigned ABa, ABb; unsigned short Cwa, Cwb;
  u32x2 DGa, DGb;

  E_LOAD(a, 0)
  E_LOAD(b, 1)
  V_LOAD(a, 0)

  int i = 0;
  while (i < cnt) {
    V_LOAD(b, i + 1)
    COMPUTE(a)
    E_LOAD(a, i + 2)
    ++i; if (i >= cnt) break;
    V_LOAD(a, i + 1)
    COMPUTE(b)
    E_LOAD(b, i + 2)
    ++i;
  }

  // store accumulators (QDEG-scaled, bf16) to the node's agg row [960]
  unsigned short* ag = aggb + (size_t)n * 960;
  ag[lane]           = f2bf(aK0  * QDEG);
  ag[96 + 3 * lane]  = f2bf(aK2x * QDEG);
  ag[97 + 3 * lane]  = f2bf(aK2y * QDEG);
  ag[98 + 3 * lane]  = f2bf(aK2z * QDEG);
  ag[480 + 5 * lane] = f2bf(aK5a * QDEG);
  ag[481 + 5 * lane] = f2bf(aK5b * QDEG);
  ag[482 + 5 * lane] = f2bf(aK5c * QDEG);
  ag[483 + 5 * lane] = f2bf(aK5d * QDEG);
  ag[484 + 5 * lane] = f2bf(aK5e * QDEG);
  if (lane < 32) {
    ag[64 + lane]      = f2bf(aK1  * QDEG);
    ag[288 + 3 * lane] = f2bf(aK3x * QDEG);
    ag[289 + 3 * lane] = f2bf(aK3y * QDEG);
    ag[290 + 3 * lane] = f2bf(aK3z * QDEG);
    ag[384 + 3 * lane] = f2bf(aK4x * QDEG);
    ag[385 + 3 * lane] = f2bf(aK4y * QDEG);
    ag[386 + 3 * lane] = f2bf(aK4z * QDEG);
    ag[800 + 5 * lane] = f2bf(aK6a * QDEG);
    ag[801 + 5 * lane] = f2bf(aK6b * QDEG);
    ag[802 + 5 * lane] = f2bf(aK6c * QDEG);
    ag[803 + 5 * lane] = f2bf(aK6d * QDEG);
    ag[804 + 5 * lane] = f2bf(aK6e * QDEG);
  }
#undef E_LOAD
#undef V_LOAD
#undef COMPUTE
}

// k_out (MFMA): out[n,0:320] = attr[n] * (A[n,0:1120] @ W).
#define ASTR 1128
__global__ __launch_bounds__(256) void k_out(
    const unsigned short* __restrict__ aggb, const float* __restrict__ xin,
    const float* __restrict__ attr, const unsigned short* __restrict__ Wp,
    float* __restrict__ out) {
  __shared__ __align__(16) unsigned short Ash[16 * ASTR];
  int t = threadIdx.x;
  int nbase = blockIdx.x * 16;
  for (int idx = t; idx < 16 * 480; idx += 256) {
    int row = idx / 480, c = idx - row * 480;
    *(unsigned*)(Ash + row * ASTR + 2 * c) =
        *(const unsigned*)(aggb + (size_t)(nbase + row) * 960 + 2 * c);
  }
  for (int idx = t; idx < 16 * 80; idx += 256) {
    int row = idx / 80, c = idx - row * 80;
    const float* xp = xin + (size_t)(nbase + row) * 160 + 2 * c;
    *(unsigned*)(Ash + row * ASTR + 960 + 2 * c) = pack2bf(xp[0], xp[1]);
  }
  __syncthreads();

  int wid = t >> 6, lane = t & 63;
  int ch = lane & 15, quad = lane >> 4;
  f32x4 acc0 = {0.f,0.f,0.f,0.f}, acc1 = {0.f,0.f,0.f,0.f};
  f32x4 acc2 = {0.f,0.f,0.f,0.f}, acc3 = {0.f,0.f,0.f,0.f};
  f32x4 acc4 = {0.f,0.f,0.f,0.f};
  const unsigned short* arow = Ash + ch * ASTR + quad * 8;
  const unsigned short* wq0 = Wp + ((size_t)(wid * 5 + 0) * 35 * 64 + lane) * 8;
  const unsigned short* wq1 = Wp + ((size_t)(wid * 5 + 1) * 35 * 64 + lane) * 8;
  const unsigned short* wq2 = Wp + ((size_t)(wid * 5 + 2) * 35 * 64 + lane) * 8;
  const unsigned short* wq3 = Wp + ((size_t)(wid * 5 + 3) * 35 * 64 + lane) * 8;
  const unsigned short* wq4 = Wp + ((size_t)(wid * 5 + 4) * 35 * 64 + lane) * 8;
  for (int ks = 0; ks < 35; ++ks) {
    bf16x8 af = *(const bf16x8*)(arow + ks * 32);
    bf16x8 w0f = *(const bf16x8*)(wq0 + ks * 512);
    bf16x8 w1f = *(const bf16x8*)(wq1 + ks * 512);
    bf16x8 w2f = *(const bf16x8*)(wq2 + ks * 512);
    bf16x8 w3f = *(const bf16x8*)(wq3 + ks * 512);
    bf16x8 w4f = *(const bf16x8*)(wq4 + ks * 512);
    acc0 = __builtin_amdgcn_mfma_f32_16x16x32_bf16(w0f, af, acc0, 0, 0, 0);
    acc1 = __builtin_amdgcn_mfma_f32_16x16x32_bf16(w1f, af, acc1, 0, 0, 0);
    acc2 = __builtin_amdgcn_mfma_f32_16x16x32_bf16(w2f, af, acc2, 0, 0, 0);
    acc3 = __builtin_amdgcn_mfma_f32_16x16x32_bf16(w3f, af, acc3, 0, 0, 0);
    acc4 = __builtin_amdgcn_mfma_f32_16x16x32_bf16(w4f, af, acc4, 0, 0, 0);
  }
  float a = attr[nbase + ch];
  float* orow = out + (size_t)(nbase + ch) * 320 + quad * 4;
  {
    float4 st = {acc0[0]*a, acc0[1]*a, acc0[2]*a, acc0[3]*a};
    *(float4*)(orow + (wid * 5 + 0) * 16) = st;
  }
  {
    float4 st = {acc1[0]*a, acc1[1]*a, acc1[2]*a, acc1[3]*a};
    *(float4*)(orow + (wid * 5 + 1) * 16) = st;
  }
  {
    float4 st = {acc2[0]*a, acc2[1]*a, acc2[2]*a, acc2[3]*a};
    *(float4*)(orow + (wid * 5 + 2) * 16) = st;
  }
  {
    float4 st = {acc3[0]*a, acc3[1]*a, acc3[2]*a, acc3[3]*a};
    *(float4*)(orow + (wid * 5 + 3) * 16) = st;
  }
  {
    float4 st = {acc4[0]*a, acc4[1]*a, acc4[2]*a, acc4[3]*a};
    *(float4*)(orow + (wid * 5 + 4) * 16) = st;
  }
}

extern "C" void kernel_launch(void* const* d_in, const int* in_sizes, int n_in,
                              void* d_out, int out_size, void* d_ws, size_t ws_size,
                              hipStream_t stream) {
  const float* node_input = (const float*)d_in[0];
  const float* node_attr  = (const float*)d_in[1];
  const int*   edge_src   = (const int*)d_in[2];
  const int*   edge_dst   = (const int*)d_in[3];
  const float* edge_attr  = (const float*)d_in[4];
  const float* ele        = (const float*)d_in[5];
  const float* sc_w0      = (const float*)d_in[6];
  const float* sc_w1      = (const float*)d_in[7];
  const float* l1_w0      = (const float*)d_in[8];
  const float* l1_w1      = (const float*)d_in[9];
  const float* fc_w0      = (const float*)d_in[10];
  const float* fc_w1      = (const float*)d_in[11];
  const float* l2_w0      = (const float*)d_in[12];
  const float* l2_w1      = (const float*)d_in[13];
  const float* l2_w2      = (const float*)d_in[14];
  float* out = (float*)d_out;

  char* base = (char*)d_ws;
  float* y              = (float*)(base);                       // 7.68 MB (stride 192)
  unsigned short* wbuf  = (unsigned short*)(base + 7680000);    // 102.4 MB packed
  float* ed2a           = (float*)(base + 110080000);           // 7.68 MB (stride 12)
  float* ed2b           = (float*)(base + 117760000);           // 5.12 MB (stride 8)
  int* counts           = (int*)(base + 122880000);
  int* offs             = (int*)(base + 122920000);
  int* cur              = (int*)(base + 122960000);
  int* order            = (int*)(base + 123000000);
  int* obeg             = (int*)(base + 123040000);
  int* ocnt             = (int*)(base + 123080000);
  int* dcur             = (int*)(base + 123120000);             // 1 KB
  unsigned short* fc1p  = (unsigned short*)(base + 123121024);  // 40 KB
  unsigned short* aggb  = (unsigned short*)(base + 123162624);  // 19.2 MB
  unsigned short* Wp    = (unsigned short*)(base + 142362624);  // 716.8 KB
  unsigned short* Wyp   = (unsigned short*)(base + 143079424);  // 61.4 KB
  unsigned short* fc0p  = (unsigned short*)(base + 143140864);  // 4 KB

  hipMemsetAsync(counts, 0, N_NODES * sizeof(int), stream);
  hipLaunchKernelGGL(k_prep, dim3(2233), dim3(256), 0, stream,
                     edge_dst, counts, fc_w1, fc1p, fc_w0, fc0p,
                     sc_w0, sc_w1, l2_w0, l2_w1, l2_w2, l1_w0, l1_w1, Wp, Wyp);
  hipLaunchKernelGGL(k_scan, dim3(1), dim3(256), 0, stream, counts, offs, cur, dcur);
  hipLaunchKernelGGL(k_perm, dim3(N_EDGES / 256), dim3(256), 0, stream,
                     edge_dst, cur, counts, offs, dcur, order, obeg, ocnt,
                     ele, edge_attr, edge_src, ed2a, ed2b);
  hipLaunchKernelGGL(k_midpre, dim3(3125), dim3(256), 0, stream,
                     ed2b, fc0p, fc1p, wbuf, node_input, node_attr, Wyp, y);
  hipLaunchKernelGGL(node_agg, dim3(2500), dim3(256), 0, stream,
                     y, ed2a, wbuf, order, obeg, ocnt, aggb);
  hipLaunchKernelGGL(k_out, dim3(625), dim3(256), 0, stream,
                     aggb, node_input, node_attr, Wp, out);
}

// Round 13
// 198.591 us; speedup vs baseline: 1.3715x; 1.1050x over previous
//
#include <hip/hip_runtime.h>
#include <cstddef>
#include <cstdint>

#define N_NODES 10000
#define N_EDGES 160000

// ---- constants ----
#define RS8    0.35355339059327373f   // 1/sqrt(8)
#define RS32   0.17677669529663687f   // 1/sqrt(32)
#define RS96   0.10206207261596575f   // 1/sqrt(96)
#define RS128  0.08838834764831845f   // 1/sqrt(128)
#define RS3    0.5773502691896258f    // 1/sqrt(3)
#define SQ3_   1.7320508075688772f
#define SQ5_   2.23606797749979f
#define A_     0.18257418583505536f   // 1/sqrt(30)
#define B_     0.31622776601683794f   // 1/sqrt(10)
#define SILU_C_ 1.6765208f
#define CS_    0.3826834323650898f    // sin(pi/8)
#define CX_    0.9238795325112867f    // cos(pi/8)
#define QDEG   0.25f                  // 1/sqrt(16)

typedef __attribute__((ext_vector_type(8))) short bf16x8;
typedef __attribute__((ext_vector_type(4))) float f32x4;

__device__ inline float bf2f(unsigned v) {
  union { unsigned u; float f; } c; c.u = v << 16; return c.f;
}
__device__ inline float bfhi(unsigned v) {   // float from HIGH 16 bits
  union { unsigned u; float f; } c; c.u = v & 0xffff0000u; return c.f;
}
__device__ inline unsigned short f2bf(float f) {
  union { float f; unsigned u; } c; c.f = f;
  unsigned r = c.u + 0x7fff + ((c.u >> 16) & 1);
  return (unsigned short)(r >> 16);
}
__device__ inline unsigned pack2bf(float a, float b) {
  return (unsigned)f2bf(a) | ((unsigned)f2bf(b) << 16);
}
__device__ inline float silu_c(float x) {
  return SILU_C_ * x / (1.f + __expf(-x));
}

// k_prep: fused (counts pre-zeroed by hipMemsetAsync):
//  blocks [0,625)     : edge-dst histogram (atomics)
//  blocks [625,713)   : fc1p (fc1 64x320 -> MFMA B-frag order) + fc0p
//                       (fc_w0 8x64 -> frag order, K padded 8->32, RS8 folded)
//  blocks [713,2233)  : Wp[1120][320] + Wyp[160][192] in the VERIFIED MFMA
//                       first-operand fragment order (scales folded)
__global__ __launch_bounds__(256) void k_prep(
    const int* __restrict__ edst, int* __restrict__ counts,
    const float* __restrict__ fc1, unsigned short* __restrict__ fc1p,
    const float* __restrict__ fc0, unsigned short* __restrict__ fc0p,
    const float* __restrict__ sc_w0, const float* __restrict__ sc_w1,
    const float* __restrict__ w0, const float* __restrict__ w1,
    const float* __restrict__ w2, const float* __restrict__ l1_w0,
    const float* __restrict__ l1_w1, unsigned short* __restrict__ Wp,
    unsigned short* __restrict__ Wyp) {
  int b = blockIdx.x, t = threadIdx.x;
  if (b < 625) {
    int e = b * 256 + t;
    if (e < N_EDGES) atomicAdd(&counts[edst[e]], 1);
    return;
  }
  if (b < 713) {
    int i = (b - 625) * 256 + t;
    if (i < 20480) {
      int j = i & 7, q = (i >> 3) & 3, n = (i >> 5) & 15, kq = (i >> 9) & 1, tt = i >> 10;
      int k = kq * 32 + q * 8 + j;
      fc1p[i] = f2bf(fc1[k * 320 + tt * 16 + n]);
    } else if (i < 22528) {
      int ii = i - 20480;
      int j = ii & 7;
      int lane = (ii >> 3) & 63;
      int ch = lane & 15, quad = lane >> 4;
      int nt = ii >> 9;                  // [0,4)
      int k = quad * 8 + j;
      float v = (k < 8) ? RS8 * fc0[k * 64 + nt * 16 + ch] : 0.f;
      fc0p[ii] = f2bf(v);
    }
    return;
  }
  int i = (b - 713) * 256 + t;
  if (i < 358400) {
    int j = i & 7;
    int lane = (i >> 3) & 63;
    int ch = lane & 15, quad = lane >> 4;
    int r = i >> 9;                    // [0,700)
    int nt = r / 35, ks = r - nt * 35;
    int k = ks * 32 + quad * 8 + j;
    int oc = nt * 16 + ch;
    float v = 0.f;
    if (k < 96) {                                   // m0 -> oc [0,64)
      if (oc < 64) v = (CX_ * RS96) * w0[k * 64 + oc];
    } else if (k < 480) {                           // m1 -> oc [64,160)
      int tt = k - 96, u = tt / 3, ii = tt - u * 3;
      if (oc >= 64 && oc < 160) {
        int d = oc - 64, vv = d / 3, jj = d - vv * 3;
        if (jj == ii) v = (CX_ * RS128) * w1[u * 32 + vv];
      }
    } else if (k < 960) {                           // m2 -> oc [160,320)
      int tt = k - 480, u = tt / 5, kk = tt - u * 5;
      if (oc >= 160) {
        int d = oc - 160, vv = d / 5, jj = d - vv * 5;
        if (jj == kk) v = RS96 * w2[u * 32 + vv];
      }
    } else if (k < 1024) {                          // x0 sc -> oc [0,64)
      int u = k - 960;
      if (oc < 64) v = (CS_ * 0.125f) * sc_w0[u * 64 + oc];
    } else {                                        // x1 sc -> oc [64,160)
      int tt = k - 1024, u = tt / 3, ii = tt - u * 3;
      if (oc >= 64 && oc < 160) {
        int d = oc - 64, vv = d / 3, jj = d - vv * 3;
        if (jj == ii) v = (CS_ * RS32) * sc_w1[u * 32 + vv];
      }
    }
    Wp[i] = f2bf(v);
  } else if (i < 358400 + 30720) {
    // Wyp: y[n, 0:192] = attr * (x[n,0:160] @ Wy). KS=5, NT=12.
    int ii2 = i - 358400;
    int j = ii2 & 7;
    int lane = (ii2 >> 3) & 63;
    int ch = lane & 15, quad = lane >> 4;
    int r = ii2 >> 9;                  // [0,60)
    int nt = r / 5, ks = r - nt * 5;
    int k = ks * 32 + quad * 8 + j;    // [0,160)
    int oc = nt * 16 + ch;             // [0,192)
    float v = 0.f;
    if (k < 64) {
      if (oc < 64) v = 0.125f * l1_w0[k * 64 + oc];
    } else {
      int tt = k - 64, u = tt / 3, ci = tt - u * 3;   // u<32, ci<3
      if (oc >= 64) {
        int d = oc - 64, vv = d >> 2, jj = d & 3;
        if (jj == ci) v = RS32 * l1_w1[u * 32 + vv];  // jj==3 never matches
      }
    }
    Wyp[ii2] = f2bf(v);
  }
}

// exclusive scan of counts -> offs/cur; degree histogram + descending-degree
// exclusive scan -> dcur (single block).
__global__ __launch_bounds__(256) void k_scan(const int* __restrict__ counts,
                                              int* __restrict__ offs,
                                              int* __restrict__ cur,
                                              int* __restrict__ dcur) {
  __shared__ int ps[256];
  __shared__ int dbin[256];
  int t = threadIdx.x;
  dbin[t] = 0;
  int base = t * 40;
  int sum = 0;
  for (int i = 0; i < 40; ++i) {
    int idx = base + i;
    if (idx < N_NODES) sum += counts[idx];
  }
  ps[t] = sum;
  __syncthreads();
  for (int off = 1; off < 256; off <<= 1) {
    int v = (t >= off) ? ps[t - off] : 0;
    __syncthreads();
    ps[t] += v;
    __syncthreads();
  }
  int run = (t == 0) ? 0 : ps[t - 1];
  for (int i = 0; i < 40; ++i) {
    int idx = base + i;
    if (idx < N_NODES) {
      int c = counts[idx];
      offs[idx] = run; cur[idx] = run;
      run += c;
      atomicAdd(&dbin[c < 255 ? c : 255], 1);
    }
  }
  __syncthreads();
  int rb = 255 - t;
  int v = dbin[rb];
  __syncthreads();
  ps[t] = v;
  __syncthreads();
  for (int off = 1; off < 256; off <<= 1) {
    int u = (t >= off) ? ps[t - off] : 0;
    __syncthreads();
    ps[t] += u;
    __syncthreads();
  }
  dcur[rb] = ps[t] - v;
}

// Permute kernel (r1/r2-verified split form): per edge compute sorted
// position p and SCATTER-WRITE two permuted streams:
//   ed2a (stride 12 f): [0..8]=SH, [9]=src, [10,11]=pad   (node_agg input)
//   ed2b (stride  8 f): ele row                            (w_gemm input)
// Also the node scatter (descending-degree rank -> order/obeg/ocnt).
__global__ __launch_bounds__(256) void k_perm(
    const int* __restrict__ edst, int* __restrict__ cur,
    const int* __restrict__ counts, const int* __restrict__ offs,
    int* __restrict__ dcur, int* __restrict__ order,
    int* __restrict__ obeg, int* __restrict__ ocnt,
    const float* __restrict__ ele, const float* __restrict__ eattr,
    const int* __restrict__ esrc, float* __restrict__ ed2a,
    float* __restrict__ ed2b) {
  __shared__ __align__(16) float sh_ea[256 * 9];
  __shared__ __align__(16) float sh_el[256 * 8];
  int t = threadIdx.x;
  int eb = blockIdx.x * 256;
  int e = eb + t;
  for (int i = t; i < 2304; i += 256) sh_ea[i] = eattr[(size_t)eb * 9 + i];
  {
    const float4* src = (const float4*)(ele + (size_t)eb * 8);
    float4* dst = (float4*)sh_el;
    dst[t] = src[t]; dst[t + 256] = src[t + 256];
  }
  __syncthreads();
  int d = edst[e];
  int p = atomicAdd(&cur[d], 1);
  const float* ea = sh_ea + t * 9;
  const float* el = sh_el + t * 8;
  float4 r0 = {ea[0], ea[1], ea[2], ea[3]};
  float4 r1 = {ea[4], ea[5], ea[6], ea[7]};
  float4 r2 = {ea[8], __int_as_float(esrc[e]), 0.f, 0.f};
  float4* da = (float4*)(ed2a + (size_t)p * 12);
  da[0] = r0; da[1] = r1; da[2] = r2;
  float4 r3 = {el[0], el[1], el[2], el[3]};
  float4 r4 = {el[4], el[5], el[6], el[7]};
  float4* db = (float4*)(ed2b + (size_t)p * 8);
  db[0] = r3; db[1] = r4;
  if (e < N_NODES) {
    int c = counts[e];
    int b = c < 255 ? c : 255;
    int q = atomicAdd(&dcur[b], 1);
    order[q] = e; obeg[q] = offs[e]; ocnt[q] = c;
  }
}

__device__ inline f32x4 wtile(const unsigned short* __restrict__ fc1p,
                              bf16x8 a0, bf16x8 a1, int mrow, int quad, int t) {
  f32x4 acc = {0.f, 0.f, 0.f, 0.f};
  bf16x8 b0 = *(const bf16x8*)(fc1p + ((size_t)((t * 2 + 0) * 16 + mrow) * 4 + quad) * 8);
  bf16x8 b1 = *(const bf16x8*)(fc1p + ((size_t)((t * 2 + 1) * 16 + mrow) * 4 + quad) * 8);
  acc = __builtin_amdgcn_mfma_f32_16x16x32_bf16(b0, a0, acc, 0, 0, 0);
  acc = __builtin_amdgcn_mfma_f32_16x16x32_bf16(b1, a1, acc, 0, 0, 0);
  return acc;
}

struct WgemmShared {
  __align__(16) unsigned short elb[64 * 32];   // 4KB: ele bf16, K padded 8->32
  __align__(16) unsigned short h[64 * 72];     // 9KB, 72-stride pad
};

// STREAMING MFMA radial GEMM: 64 edges/block, reads ele from ed2b
// (sequential, stride 8 f). h-phase MFMA (verified r7); pack-phase writes
// packed wbuf (640 B/edge).
__device__ void w_gemm_body(WgemmShared& sh, int blk,
    const float* __restrict__ ed2b, const unsigned short* __restrict__ fc0p,
    const unsigned short* __restrict__ fc1p, unsigned short* __restrict__ wout) {
  int t = threadIdx.x;
  int eb = blk * 64;
  {
    int e = t >> 2, q = t & 3;
    uint4 pk = {0u, 0u, 0u, 0u};
    if (q == 0) {
      const float4* ep = (const float4*)(ed2b + (size_t)(eb + e) * 8);
      float4 u = ep[0], v = ep[1];
      pk.x = pack2bf(u.x, u.y); pk.y = pack2bf(u.z, u.w);
      pk.z = pack2bf(v.x, v.y); pk.w = pack2bf(v.z, v.w);
    }
    *(uint4*)(sh.elb + e * 32 + q * 8) = pk;
  }
  __syncthreads();

  int wv = t >> 6, lane = t & 63;
  int ch16 = lane & 15, quad = lane >> 4;
  {
    bf16x8 af = *(const bf16x8*)(sh.elb + (wv * 16 + ch16) * 32 + quad * 8);
    bf16x8 b0 = *(const bf16x8*)(fc0p + 0 * 512 + lane * 8);
    bf16x8 b1 = *(const bf16x8*)(fc0p + 1 * 512 + lane * 8);
    bf16x8 b2 = *(const bf16x8*)(fc0p + 2 * 512 + lane * 8);
    bf16x8 b3 = *(const bf16x8*)(fc0p + 3 * 512 + lane * 8);
    f32x4 z = {0.f, 0.f, 0.f, 0.f};
    f32x4 h0 = __builtin_amdgcn_mfma_f32_16x16x32_bf16(b0, af, z, 0, 0, 0);
    f32x4 h1 = __builtin_amdgcn_mfma_f32_16x16x32_bf16(b1, af, z, 0, 0, 0);
    f32x4 h2 = __builtin_amdgcn_mfma_f32_16x16x32_bf16(b2, af, z, 0, 0, 0);
    f32x4 h3 = __builtin_amdgcn_mfma_f32_16x16x32_bf16(b3, af, z, 0, 0, 0);
    unsigned short* hb = sh.h + (wv * 16 + ch16) * 72 + quad * 4;
    uint2 s;
    s.x = pack2bf(silu_c(h0[0]), silu_c(h0[1]));
    s.y = pack2bf(silu_c(h0[2]), silu_c(h0[3]));
    *(uint2*)(hb + 0) = s;
    s.x = pack2bf(silu_c(h1[0]), silu_c(h1[1]));
    s.y = pack2bf(silu_c(h1[2]), silu_c(h1[3]));
    *(uint2*)(hb + 16) = s;
    s.x = pack2bf(silu_c(h2[0]), silu_c(h2[1]));
    s.y = pack2bf(silu_c(h2[2]), silu_c(h2[3]));
    *(uint2*)(hb + 32) = s;
    s.x = pack2bf(silu_c(h3[0]), silu_c(h3[1]));
    s.y = pack2bf(silu_c(h3[2]), silu_c(h3[3]));
    *(uint2*)(hb + 48) = s;
  }
  __syncthreads();

  int m0 = wv * 16;
  int mrow = lane & 15;
  bf16x8 a0 = *(const bf16x8*)(sh.h + (m0 + mrow) * 72 + quad * 8);
  bf16x8 a1 = *(const bf16x8*)(sh.h + (m0 + mrow) * 72 + 32 + quad * 8);
  char* wbase = (char*)wout + (size_t)(eb + m0 + mrow) * 640;
  const float K = 0.125f;
  #pragma unroll
  for (int tt = 0; tt < 4; ++tt) {
    f32x4 Av = wtile(fc1p, a0, a1, mrow, quad, tt);
    f32x4 Bv = wtile(fc1p, a0, a1, mrow, quad, tt + 4);
    uint4 st;
    st.x = pack2bf(Av[0] * K, Bv[0] * K);
    st.y = pack2bf(Av[1] * K, Bv[1] * K);
    st.z = pack2bf(Av[2] * K, Bv[2] * K);
    st.w = pack2bf(Av[3] * K, Bv[3] * K);
    *(uint4*)(wbase + 64 * tt + 16 * quad) = st;
  }
  #pragma unroll
  for (int tt = 8; tt < 12; ++tt) {
    f32x4 Cv = wtile(fc1p, a0, a1, mrow, quad, tt);
    uint2 st;
    st.x = pack2bf(Cv[0] * K, Cv[1] * K);
    st.y = pack2bf(Cv[2] * K, Cv[3] * K);
    *(uint2*)(wbase + 256 + 32 * (tt - 8) + 8 * quad) = st;
  }
  #pragma unroll
  for (int tt = 12; tt < 14; ++tt) {
    f32x4 Dv = wtile(fc1p, a0, a1, mrow, quad, tt);
    f32x4 Ev = wtile(fc1p, a0, a1, mrow, quad, tt + 2);
    f32x4 Fv = wtile(fc1p, a0, a1, mrow, quad, tt + 4);
    f32x4 Gv = wtile(fc1p, a0, a1, mrow, quad, tt + 6);
    char* db = wbase + 384 + 128 * (tt - 12) + 32 * quad;
    uint4 s0, s1;
    s0.x = pack2bf(Dv[0] * K, Ev[0] * K); s0.y = pack2bf(Fv[0] * K, Gv[0] * K);
    s0.z = pack2bf(Dv[1] * K, Ev[1] * K); s0.w = pack2bf(Fv[1] * K, Gv[1] * K);
    s1.x = pack2bf(Dv[2] * K, Ev[2] * K); s1.y = pack2bf(Fv[2] * K, Gv[2] * K);
    s1.z = pack2bf(Dv[3] * K, Ev[3] * K); s1.w = pack2bf(Fv[3] * K, Gv[3] * K);
    *(uint4*)(db) = s0;
    *(uint4*)(db + 16) = s1;
  }
}

// k_npre body (MFMA): y[n, 0:192] = attr[n] * (bf16(xin[n,0:160]) @ Wyp).
#define YSTR 168
__device__ void npre_body(unsigned short* Ash, int blk,
    const float* __restrict__ xin, const float* __restrict__ attr,
    const unsigned short* __restrict__ Wyp, float* __restrict__ y) {
  int t = threadIdx.x;
  int nbase = blk * 16;
  for (int idx = t; idx < 16 * 80; idx += 256) {
    int row = idx / 80, c = idx - row * 80;
    const float* xp = xin + (size_t)(nbase + row) * 160 + 2 * c;
    *(unsigned*)(Ash + row * YSTR + 2 * c) = pack2bf(xp[0], xp[1]);
  }
  __syncthreads();
  int wid = t >> 6, lane = t & 63;
  int ch = lane & 15, quad = lane >> 4;
  const unsigned short* arow = Ash + ch * YSTR + quad * 8;
  f32x4 acc0 = {0.f,0.f,0.f,0.f}, acc1 = {0.f,0.f,0.f,0.f}, acc2 = {0.f,0.f,0.f,0.f};
  const unsigned short* wq0 = Wyp + ((size_t)(wid * 3 + 0) * 5 * 64 + lane) * 8;
  const unsigned short* wq1 = Wyp + ((size_t)(wid * 3 + 1) * 5 * 64 + lane) * 8;
  const unsigned short* wq2 = Wyp + ((size_t)(wid * 3 + 2) * 5 * 64 + lane) * 8;
  #pragma unroll
  for (int ks = 0; ks < 5; ++ks) {
    bf16x8 af  = *(const bf16x8*)(arow + ks * 32);
    bf16x8 w0f = *(const bf16x8*)(wq0 + ks * 512);
    bf16x8 w1f = *(const bf16x8*)(wq1 + ks * 512);
    bf16x8 w2f = *(const bf16x8*)(wq2 + ks * 512);
    acc0 = __builtin_amdgcn_mfma_f32_16x16x32_bf16(w0f, af, acc0, 0, 0, 0);
    acc1 = __builtin_amdgcn_mfma_f32_16x16x32_bf16(w1f, af, acc1, 0, 0, 0);
    acc2 = __builtin_amdgcn_mfma_f32_16x16x32_bf16(w2f, af, acc2, 0, 0, 0);
  }
  float a = attr[nbase + ch];
  float* yrow = y + (size_t)(nbase + ch) * 192 + quad * 4;
  { float4 st = {acc0[0]*a, acc0[1]*a, acc0[2]*a, acc0[3]*a};
    *(float4*)(yrow + (wid * 3 + 0) * 16) = st; }
  { float4 st = {acc1[0]*a, acc1[1]*a, acc1[2]*a, acc1[3]*a};
    *(float4*)(yrow + (wid * 3 + 1) * 16) = st; }
  { float4 st = {acc2[0]*a, acc2[1]*a, acc2[2]*a, acc2[3]*a};
    *(float4*)(yrow + (wid * 3 + 2) * 16) = st; }
}

// fused mid-stage: blocks [0,2500) = w_gemm, [2500,3125) = npre
__global__ __launch_bounds__(256) void k_midpre(
    const float* __restrict__ ed2b, const unsigned short* __restrict__ fc0p,
    const unsigned short* __restrict__ fc1p, unsigned short* __restrict__ wout,
    const float* __restrict__ xin, const float* __restrict__ attr,
    const unsigned short* __restrict__ Wyp, float* __restrict__ y) {
  __shared__ union ShU {
    WgemmShared w;
    unsigned short ash[16 * YSTR];
  } sh;
  if (blockIdx.x < 2500) {
    w_gemm_body(sh.w, blockIdx.x, ed2b, fc0p, fc1p, wout);
  } else {
    npre_body(sh.ash, blockIdx.x - 2500, xin, attr, Wyp, y);
  }
}

// node_agg: the r8-proven optimum — 1 node/wave, grid 2500, round-0 2-slot
// pipeline, no LDS, plain loads. Eight structural/cache interventions
// (r1,r2,r3,r9,r10,r11,r12) all regressed; this is the verified best form.
__global__ __launch_bounds__(256) void node_agg(
    const float* __restrict__ y, const float* __restrict__ ed2a,
    const unsigned short* __restrict__ wbuf,
    const int* __restrict__ order, const int* __restrict__ obeg,
    const int* __restrict__ ocnt, unsigned short* __restrict__ aggb) {
  int tid = threadIdx.x, wid = tid >> 6, lane = tid & 63, l31 = lane & 31;
  int gw = blockIdx.x * 4 + wid;
  // fixed per-lane byte offsets (loop-invariant)
  int voY  = 4 * lane;           // y scalar block
  int voX  = 256 + 16 * l31;     // y vector float4 {x0,x1,x2,0}
  int voAB = 4 * lane;           // wbuf AB
  int voC  = 256 + 2 * lane;     // wbuf C
  int voDG = 384 + 8 * l31;      // wbuf DEFG

#define E_LOAD(S, idx)                                                         \
  if ((idx) < cnt) {                                                           \
    const float4* ep = (const float4*)(ed2a + (size_t)(beg + (idx)) * 12);     \
    PE0##S = ep[0]; PE1##S = ep[1]; PE2##S = ep[2];                            \
  }
#define V_LOAD(S, idx)                                                         \
  if ((idx) < cnt) {                                                           \
    int srcn = __float_as_int(PE2##S.y);                                       \
    const char* yb = (const char*)y + (size_t)srcn * 768;                      \
    Y##S = *(const float*)(yb + voY);                                          \
    X##S = *(const f32x4*)(yb + voX);                                          \
    const char* wb = (const char*)wbuf + (size_t)(beg + (idx)) * 640;          \
    AB##S = *(const unsigned*)(wb + voAB);                                     \
    Cw##S = *(const unsigned short*)(wb + voC);                                \
    DG##S = *(const uint2*)(wb + voDG);                                        \
  }
#define COMPUTE(S)                                                             \
  {                                                                            \
    float e0 = PE0##S.x, ey = PE0##S.y, ez = PE0##S.z, ex = PE0##S.w;          \
    float q0 = PE1##S.x, q1 = PE1##S.y, q2 = PE1##S.z, q3 = PE1##S.w;          \
    float q4 = PE2##S.x;                                                       \
    float Yv = Y##S, x0 = X##S.x, x1 = X##S.y, x2 = X##S.z;                    \
    float vA = bf2f(AB##S), vB = bfhi(AB##S), vC = bf2f(Cw##S);                \
    float vD = bf2f(DG##S.x), vE = bfhi(DG##S.x);                              \
    float vF = bf2f(DG##S.y), vG = bfhi(DG##S.y);                              \
    aK0 += Yv * e0 * vA;                                                       \
    float tB = Yv * vB; aK2x += tB * ey; aK2y += tB * ez; aK2z += tB * ex;     \
    float tC = Yv * vC;                                                        \
    aK5a += tC * q0; aK5b += tC * q1; aK5c += tC * q2;                         \
    aK5d += tC * q3; aK5e += tC * q4;                                          \
    float t1 = x0 * ey + x1 * ez + x2 * ex; aK1 += (RS3 * vE) * t1;            \
    float s3 = e0 * vD; aK3x += x0 * s3; aK3y += x1 * s3; aK3z += x2 * s3;     \
    float s4 = SQ3_ * vG;                                                      \
    aK4x += s4 * (B_ * (x2 * q0 + x1 * q1 - x0 * q4) - A_ * x0 * q2);          \
    aK4y += s4 * (B_ * (x0 * q1 + x2 * q3) + 2.f * A_ * x1 * q2);              \
    aK4z += s4 * (B_ * (x0 * q0 + x1 * q3 + x2 * q4) - A_ * x2 * q2);          \
    float s6 = SQ5_ * vF;                                                      \
    aK6a += s6 * (-B_ * (x0 * ex + x2 * ey));                                  \
    aK6b += s6 * (-B_ * (x0 * ez + x1 * ey));                                  \
    aK6c += s6 * ( A_ * (x0 * ey + x2 * ex - 2.f * x1 * ez));                  \
    aK6d += s6 * (-B_ * (x1 * ex + x2 * ez));                                  \
    aK6e += s6 * ( B_ * (x0 * ey - x2 * ex));                                  \
  }

  int n = order[gw], beg = obeg[gw], cnt = ocnt[gw];

  float aK0 = 0.f, aK2x = 0.f, aK2y = 0.f, aK2z = 0.f;
  float aK5a = 0.f, aK5b = 0.f, aK5c = 0.f, aK5d = 0.f, aK5e = 0.f;
  float aK1 = 0.f, aK3x = 0.f, aK3y = 0.f, aK3z = 0.f;
  float aK4x = 0.f, aK4y = 0.f, aK4z = 0.f;
  float aK6a = 0.f, aK6b = 0.f, aK6c = 0.f, aK6d = 0.f, aK6e = 0.f;

  float4 PE0a, PE1a, PE2a, PE0b, PE1b, PE2b;
  float Ya, Yb; f32x4 Xa, Xb;
  unsigned ABa, ABb; unsigned short Cwa, Cwb;
  uint2 DGa, DGb;

  E_LOAD(a, 0)
  E_LOAD(b, 1)
  V_LOAD(a, 0)

  int i = 0;
  while (i < cnt) {
    V_LOAD(b, i + 1)
    COMPUTE(a)
    E_LOAD(a, i + 2)
    ++i; if (i >= cnt) break;
    V_LOAD(a, i + 1)
    COMPUTE(b)
    E_LOAD(b, i + 2)
    ++i;
  }

  // store accumulators (QDEG-scaled, bf16) to the node's agg row [960]
  unsigned short* ag = aggb + (size_t)n * 960;
  ag[lane]           = f2bf(aK0  * QDEG);
  ag[96 + 3 * lane]  = f2bf(aK2x * QDEG);
  ag[97 + 3 * lane]  = f2bf(aK2y * QDEG);
  ag[98 + 3 * lane]  = f2bf(aK2z * QDEG);
  ag[480 + 5 * lane] = f2bf(aK5a * QDEG);
  ag[481 + 5 * lane] = f2bf(aK5b * QDEG);
  ag[482 + 5 * lane] = f2bf(aK5c * QDEG);
  ag[483 + 5 * lane] = f2bf(aK5d * QDEG);
  ag[484 + 5 * lane] = f2bf(aK5e * QDEG);
  if (lane < 32) {
    ag[64 + lane]      = f2bf(aK1  * QDEG);
    ag[288 + 3 * lane] = f2bf(aK3x * QDEG);
    ag[289 + 3 * lane] = f2bf(aK3y * QDEG);
    ag[290 + 3 * lane] = f2bf(aK3z * QDEG);
    ag[384 + 3 * lane] = f2bf(aK4x * QDEG);
    ag[385 + 3 * lane] = f2bf(aK4y * QDEG);
    ag[386 + 3 * lane] = f2bf(aK4z * QDEG);
    ag[800 + 5 * lane] = f2bf(aK6a * QDEG);
    ag[801 + 5 * lane] = f2bf(aK6b * QDEG);
    ag[802 + 5 * lane] = f2bf(aK6c * QDEG);
    ag[803 + 5 * lane] = f2bf(aK6d * QDEG);
    ag[804 + 5 * lane] = f2bf(aK6e * QDEG);
  }
#undef E_LOAD
#undef V_LOAD
#undef COMPUTE
}

// k_out (MFMA): out[n,0:320] = attr[n] * (A[n,0:1120] @ W).
#define ASTR 1128
__global__ __launch_bounds__(256) void k_out(
    const unsigned short* __restrict__ aggb, const float* __restrict__ xin,
    const float* __restrict__ attr, const unsigned short* __restrict__ Wp,
    float* __restrict__ out) {
  __shared__ __align__(16) unsigned short Ash[16 * ASTR];
  int t = threadIdx.x;
  int nbase = blockIdx.x * 16;
  for (int idx = t; idx < 16 * 480; idx += 256) {
    int row = idx / 480, c = idx - row * 480;
    *(unsigned*)(Ash + row * ASTR + 2 * c) =
        *(const unsigned*)(aggb + (size_t)(nbase + row) * 960 + 2 * c);
  }
  for (int idx = t; idx < 16 * 80; idx += 256) {
    int row = idx / 80, c = idx - row * 80;
    const float* xp = xin + (size_t)(nbase + row) * 160 + 2 * c;
    *(unsigned*)(Ash + row * ASTR + 960 + 2 * c) = pack2bf(xp[0], xp[1]);
  }
  __syncthreads();

  int wid = t >> 6, lane = t & 63;
  int ch = lane & 15, quad = lane >> 4;
  f32x4 acc0 = {0.f,0.f,0.f,0.f}, acc1 = {0.f,0.f,0.f,0.f};
  f32x4 acc2 = {0.f,0.f,0.f,0.f}, acc3 = {0.f,0.f,0.f,0.f};
  f32x4 acc4 = {0.f,0.f,0.f,0.f};
  const unsigned short* arow = Ash + ch * ASTR + quad * 8;
  const unsigned short* wq0 = Wp + ((size_t)(wid * 5 + 0) * 35 * 64 + lane) * 8;
  const unsigned short* wq1 = Wp + ((size_t)(wid * 5 + 1) * 35 * 64 + lane) * 8;
  const unsigned short* wq2 = Wp + ((size_t)(wid * 5 + 2) * 35 * 64 + lane) * 8;
  const unsigned short* wq3 = Wp + ((size_t)(wid * 5 + 3) * 35 * 64 + lane) * 8;
  const unsigned short* wq4 = Wp + ((size_t)(wid * 5 + 4) * 35 * 64 + lane) * 8;
  for (int ks = 0; ks < 35; ++ks) {
    bf16x8 af = *(const bf16x8*)(arow + ks * 32);
    bf16x8 w0f = *(const bf16x8*)(wq0 + ks * 512);
    bf16x8 w1f = *(const bf16x8*)(wq1 + ks * 512);
    bf16x8 w2f = *(const bf16x8*)(wq2 + ks * 512);
    bf16x8 w3f = *(const bf16x8*)(wq3 + ks * 512);
    bf16x8 w4f = *(const bf16x8*)(wq4 + ks * 512);
    acc0 = __builtin_amdgcn_mfma_f32_16x16x32_bf16(w0f, af, acc0, 0, 0, 0);
    acc1 = __builtin_amdgcn_mfma_f32_16x16x32_bf16(w1f, af, acc1, 0, 0, 0);
    acc2 = __builtin_amdgcn_mfma_f32_16x16x32_bf16(w2f, af, acc2, 0, 0, 0);
    acc3 = __builtin_amdgcn_mfma_f32_16x16x32_bf16(w3f, af, acc3, 0, 0, 0);
    acc4 = __builtin_amdgcn_mfma_f32_16x16x32_bf16(w4f, af, acc4, 0, 0, 0);
  }
  float a = attr[nbase + ch];
  float* orow = out + (size_t)(nbase + ch) * 320 + quad * 4;
  {
    float4 st = {acc0[0]*a, acc0[1]*a, acc0[2]*a, acc0[3]*a};
    *(float4*)(orow + (wid * 5 + 0) * 16) = st;
  }
  {
    float4 st = {acc1[0]*a, acc1[1]*a, acc1[2]*a, acc1[3]*a};
    *(float4*)(orow + (wid * 5 + 1) * 16) = st;
  }
  {
    float4 st = {acc2[0]*a, acc2[1]*a, acc2[2]*a, acc2[3]*a};
    *(float4*)(orow + (wid * 5 + 2) * 16) = st;
  }
  {
    float4 st = {acc3[0]*a, acc3[1]*a, acc3[2]*a, acc3[3]*a};
    *(float4*)(orow + (wid * 5 + 3) * 16) = st;
  }
  {
    float4 st = {acc4[0]*a, acc4[1]*a, acc4[2]*a, acc4[3]*a};
    *(float4*)(orow + (wid * 5 + 4) * 16) = st;
  }
}

extern "C" void kernel_launch(void* const* d_in, const int* in_sizes, int n_in,
                              void* d_out, int out_size, void* d_ws, size_t ws_size,
                              hipStream_t stream) {
  const float* node_input = (const float*)d_in[0];
  const float* node_attr  = (const float*)d_in[1];
  const int*   edge_src   = (const int*)d_in[2];
  const int*   edge_dst   = (const int*)d_in[3];
  const float* edge_attr  = (const float*)d_in[4];
  const float* ele        = (const float*)d_in[5];
  const float* sc_w0      = (const float*)d_in[6];
  const float* sc_w1      = (const float*)d_in[7];
  const float* l1_w0      = (const float*)d_in[8];
  const float* l1_w1      = (const float*)d_in[9];
  const float* fc_w0      = (const float*)d_in[10];
  const float* fc_w1      = (const float*)d_in[11];
  const float* l2_w0      = (const float*)d_in[12];
  const float* l2_w1      = (const float*)d_in[13];
  const float* l2_w2      = (const float*)d_in[14];
  float* out = (float*)d_out;

  char* base = (char*)d_ws;
  float* y              = (float*)(base);                       // 7.68 MB (stride 192)
  unsigned short* wbuf  = (unsigned short*)(base + 7680000);    // 102.4 MB packed
  float* ed2a           = (float*)(base + 110080000);           // 7.68 MB (stride 12)
  float* ed2b           = (float*)(base + 117760000);           // 5.12 MB (stride 8)
  int* counts           = (int*)(base + 122880000);
  int* offs             = (int*)(base + 122920000);
  int* cur              = (int*)(base + 122960000);
  int* order            = (int*)(base + 123000000);
  int* obeg             = (int*)(base + 123040000);
  int* ocnt             = (int*)(base + 123080000);
  int* dcur             = (int*)(base + 123120000);             // 1 KB
  unsigned short* fc1p  = (unsigned short*)(base + 123121024);  // 40 KB
  unsigned short* aggb  = (unsigned short*)(base + 123162624);  // 19.2 MB
  unsigned short* Wp    = (unsigned short*)(base + 142362624);  // 716.8 KB
  unsigned short* Wyp   = (unsigned short*)(base + 143079424);  // 61.4 KB
  unsigned short* fc0p  = (unsigned short*)(base + 143140864);  // 4 KB

  hipMemsetAsync(counts, 0, N_NODES * sizeof(int), stream);
  hipLaunchKernelGGL(k_prep, dim3(2233), dim3(256), 0, stream,
                     edge_dst, counts, fc_w1, fc1p, fc_w0, fc0p,
                     sc_w0, sc_w1, l2_w0, l2_w1, l2_w2, l1_w0, l1_w1, Wp, Wyp);
  hipLaunchKernelGGL(k_scan, dim3(1), dim3(256), 0, stream, counts, offs, cur, dcur);
  hipLaunchKernelGGL(k_perm, dim3(N_EDGES / 256), dim3(256), 0, stream,
                     edge_dst, cur, counts, offs, dcur, order, obeg, ocnt,
                     ele, edge_attr, edge_src, ed2a, ed2b);
  hipLaunchKernelGGL(k_midpre, dim3(3125), dim3(256), 0, stream,
                     ed2b, fc0p, fc1p, wbuf, node_input, node_attr, Wyp, y);
  hipLaunchKernelGGL(node_agg, dim3(2500), dim3(256), 0, stream,
                     y, ed2a, wbuf, order, obeg, ocnt, aggb);
  hipLaunchKernelGGL(k_out, dim3(625), dim3(256), 0, stream,
                     aggb, node_input, node_attr, Wp, out);
}